// Round 13
// baseline (777.008 us; speedup 1.0000x reference)
//
#include <hip/hip_runtime.h>

#define NB 4096

typedef __attribute__((ext_vector_type(8)))  __bf16 bf16x8;
typedef __attribute__((ext_vector_type(4)))  float  f32x4;
typedef __attribute__((ext_vector_type(16))) float  f32x16;
typedef __attribute__((ext_vector_type(8)))  int    i32x8;
typedef __attribute__((ext_vector_type(4)))  int    i32x4;

// gelu tanh-approx via sigmoid identity: x * rcp(1 + exp(-2y)), y = x(c0 + c1 x^2)
__device__ __forceinline__ float gelu_fast(float x){
    float x2 = x * x;
    float z  = x * (-1.59576912f - 0.07135482f * x2);   // -2y
    float e  = __expf(z);
    return x * __builtin_amdgcn_rcpf(1.0f + e);
}
__device__ __forceinline__ unsigned short f2bf(float x){
    unsigned b = __float_as_uint(x);
    b += 0x7fffu + ((b >> 16) & 1u);
    return (unsigned short)(b >> 16);
}
// e2m1 fp4 code: values {0,0.5,1,1.5,2,3,4,6} = codes 0..7, sign bit 3.
__device__ __forceinline__ unsigned f2fp4(float x){
    unsigned s = (__float_as_uint(x) >> 31) & 1u;
    float m = fabsf(x);
    int c;
    if      (m < 0.25f) c = 0;
    else if (m < 0.75f) c = 1;
    else if (m < 1.25f) c = 2;
    else if (m < 1.75f) c = 3;
    else if (m < 2.5f)  c = 4;
    else if (m < 3.5f)  c = 5;
    else if (m < 5.0f)  c = 6;
    else                c = 7;
    return (s << 3) | (unsigned)c;
}

// ---------------- pack offsets (elements) ----------------
#define O_WP0  0
#define O_WP1  40960
#define O_WP2  368640
#define O_PROJ 696320
#define O_VAL1 761856
#define O_POS1 827392
#define O_RES1 892928
#define O_VAL2 958464
#define O_RES2 991232
#define O_POS2 1515520
#define O_MIX  1519616
#define PK_TOTAL 1523712

#define WQ4_BYTES 163840   // 256*1280 fp4 nibbles per conv layer

__device__ __forceinline__ unsigned short pack_std_elem(const float* W, int N, int t){
    int j = t & 7, lane = (t >> 3) & 63, rest = t >> 9;
    int ntcnt = N >> 4;
    int nt = rest % ntcnt, kk = rest / ntcnt;
    int n = nt*16 + (lane & 15), k = kk*32 + ((lane >> 4) << 3) + j;
    return f2bf(W[k * N + n]);
}
__device__ __forceinline__ unsigned short pack_pad_elem(const float* W, int Nreal, int t){
    int j = t & 7, lane = (t >> 3) & 63, kk = t >> 9;
    int n = lane & 15, k = kk*32 + ((lane >> 4) << 3) + j;
    return (n < Nreal) ? f2bf(W[k * Nreal + n]) : (unsigned short)0;
}
// fp4 conv pack for mfma_scale 32x32x64 (fmt=4): per lane 32 k-elems = 16 B, LSB-first.
__device__ __forceinline__ unsigned char pack_fp4_byte(const float* W, int t){
    int byt = t & 15, lane = (t >> 4) & 63, g = (t >> 10) & 7, S = t >> 13;
    int n = g*32 + (lane & 31);
    int kbase = S*64 + ((lane >> 5) << 5) + (byt << 1);
    int k0 = kbase, k1 = kbase + 1;
    float v0 = W[n*1280 + (k0 & 255)*5 + (k0 >> 8)] * 64.0f;
    float v1 = W[n*1280 + (k1 & 255)*5 + (k1 >> 8)] * 64.0f;
    return (unsigned char)(f2fp4(v0) | (f2fp4(v1) << 4));
}

__global__ __launch_bounds__(256) void pack_weights(
    const float* __restrict__ W0, const float* __restrict__ W1, const float* __restrict__ W2,
    const float* __restrict__ proj_w, const float* __restrict__ val_w1,
    const float* __restrict__ pos_w1, const float* __restrict__ res_w1,
    const float* __restrict__ val_w2, const float* __restrict__ res_w2,
    const float* __restrict__ pos_w2, const float* __restrict__ mix_w,
    unsigned short* __restrict__ pk,
    unsigned char* __restrict__ wq1, unsigned char* __restrict__ wq2)
{
    int idx = blockIdx.x * 256 + threadIdx.x;
    if (idx >= PK_TOTAL) return;
    if (idx < O_WP1){
        int t = idx;
        int j = t & 7, lane = (t >> 3) & 63, nt = (t >> 9) & 7, s = t >> 12;   // s 0..9
        int co = nt*32 + (lane & 31);
        int tap = s >> 1, ci = ((s & 1) << 4) + ((lane >> 5) << 3) + j;
        pk[idx] = f2bf(W0[co*160 + ci*5 + tap]);
    } else if (idx < O_WP1 + WQ4_BYTES){
        wq1[idx - O_WP1] = pack_fp4_byte(W1, idx - O_WP1);
    } else if (idx < O_WP2){
        // gap
    } else if (idx < O_WP2 + WQ4_BYTES){
        wq2[idx - O_WP2] = pack_fp4_byte(W2, idx - O_WP2);
    } else if (idx < O_PROJ){
        // gap
    }
    else if (idx < O_VAL1) pk[idx] = pack_std_elem(proj_w, 256, idx - O_PROJ);
    else if (idx < O_POS1) pk[idx] = pack_std_elem(val_w1, 256, idx - O_VAL1);
    else if (idx < O_RES1) pk[idx] = pack_std_elem(pos_w1, 256, idx - O_POS1);
    else if (idx < O_VAL2) pk[idx] = pack_std_elem(res_w1, 256, idx - O_RES1);
    else if (idx < O_RES2) pk[idx] = pack_std_elem(val_w2, 128, idx - O_VAL2);
    else if (idx < O_POS2) pk[idx] = pack_std_elem(res_w2, 2048, idx - O_RES2);
    else if (idx < O_MIX)  pk[idx] = pack_pad_elem(pos_w2, 4, idx - O_POS2);
    else                   pk[idx] = pack_pad_elem(mix_w, 2, idx - O_MIX);
}

// ---------------- Kernel 1: MX fp4 x fp4 conv, 256 thr, 1 batch/block, 4 waves/SIMD ----------------
// R12 design (correctness-verified) with register-safe operand construction:
// all MFMA operands built as SSA values via shufflevector — no address-taken
// partial writes into ext_vector arrays (rule #20 scratch bug fixed).
#define HT4_S 136
#define XT_S 40
#define INV512 0.001953125f
#define SCALE1 0x7F

__global__ __launch_bounds__(256, 4) void conv_mfma_kernel(
    const float* __restrict__ A,
    const float* __restrict__ B0, const float* __restrict__ B1, const float* __restrict__ B2,
    const unsigned short* __restrict__ wp0,
    const unsigned char* __restrict__ wq1, const unsigned char* __restrict__ wq2,
    unsigned short* __restrict__ pooled)
{
    __shared__ __align__(16) unsigned short xt[68 * XT_S];
    __shared__ __align__(16) unsigned char  ht4[68 * HT4_S];

    const int tid  = threadIdx.x;
    const int b    = blockIdx.x;
    const int w    = tid >> 6;        // 0..3: 64-col output group
    const int lane = tid & 63;
    const int l31  = lane & 31;
    const int hi   = lane >> 5;
    const int hi8  = hi << 3;
    const int w64  = w << 6;

    // zero halo rows (taps reach rows 0,1,66,67)
    for (int i = tid; i < 4 * HT4_S; i += 256){
        int r = i / HT4_S, c = i - r * HT4_S;
        int rr = (r < 2 ? r : r + 64);
        ht4[rr * HT4_S + c] = 0;
    }
    if (tid < 128){
        int r = tid >> 5, c = tid & 31;
        int rr = (r < 2 ? r : r + 64);
        xt[rr * XT_S + c] = 0;
    }
    // pack input: 256 threads cover the batch (256*8 = 2048 elems)
    {
        const float* Ab = A + (size_t)b * 2048;
        int e0 = tid << 3;
        int t = e0 >> 5, c = e0 & 31;
        const float4* p = (const float4*)(Ab + e0);
        float4 v0 = p[0], v1 = p[1];
        union { unsigned short u[8]; bf16x8 v; } pkv;
        pkv.u[0]=f2bf(v0.x); pkv.u[1]=f2bf(v0.y); pkv.u[2]=f2bf(v0.z); pkv.u[3]=f2bf(v0.w);
        pkv.u[4]=f2bf(v1.x); pkv.u[5]=f2bf(v1.y); pkv.u[6]=f2bf(v1.z); pkv.u[7]=f2bf(v1.w);
        *(bf16x8*)&xt[(t + 2) * XT_S + c] = pkv.v;
    }
    __syncthreads();

    f32x16 acc[2][2];   // [mt][nn]

#define ZEROALL \
    { _Pragma("unroll") for (int mt = 0; mt < 2; ++mt) \
      _Pragma("unroll") for (int nn = 0; nn < 2; ++nn) \
      _Pragma("unroll") for (int r = 0; r < 16; ++r) acc[mt][nn][r] = 0.f; }

// ----- bf16 conv0 pieces (xt + wp0); fragment indexing verified R2-R12 -----
#define LOADAX(BUF, S) \
    { _Pragma("unroll") for (int mt = 0; mt < 2; ++mt) \
          BUF[mt] = *(const bf16x8*)&xt[((mt << 5) + l31 + ((S) >> 1)) * XT_S + (((S) & 1) << 4) + hi8]; }
#define LOADB0(BUF, S) \
    { _Pragma("unroll") for (int nn = 0; nn < 2; ++nn) \
          BUF[nn] = *(const bf16x8*)(b0ptr + nn * 512 + (S) * 4096); }
#define MFX(X_, B_) \
    { _Pragma("unroll") for (int mt = 0; mt < 2; ++mt) \
      _Pragma("unroll") for (int nn = 0; nn < 2; ++nn) \
          acc[mt][nn] = __builtin_amdgcn_mfma_f32_32x32x16_bf16(X_[mt], B_[nn], acc[mt][nn], 0, 0, 0); }

// ----- MX fp4 pieces: A from ht4, B from wq (both fmt=4; verified R12) -----
// Register-safe: load i32x4 value, widen to i32x8 via shufflevector (pure SSA, no addr-taken).
#define ZERO4 ((i32x4){0,0,0,0})
#define WIDEN(T_) __builtin_shufflevector((T_), ZERO4, 0, 1, 2, 3, 4, 5, 6, 7)
// A: row = mt*32 + l31 + tap(S>>2); byte off = (S&3)*32 + hi*16 (16 contig bytes = 32 chans)
#define LOADA4(BUF, S) \
    { _Pragma("unroll") for (int mt = 0; mt < 2; ++mt){ \
          i32x4 t_ = *(const i32x4*)&ht4[((mt << 5) + l31 + ((S) >> 2)) * HT4_S + (((S) & 3) << 5) + (hi << 4)]; \
          BUF[mt] = WIDEN(t_); } }
#define LOADB4(BUF, S, BPTR) \
    { _Pragma("unroll") for (int nn = 0; nn < 2; ++nn){ \
          i32x4 t_ = *(const i32x4*)((BPTR) + (size_t)(S) * 8192 + nn * 1024); \
          BUF[nn] = WIDEN(t_); } }
#define MFMX44(A_, B_) \
    { _Pragma("unroll") for (int mt = 0; mt < 2; ++mt) \
      _Pragma("unroll") for (int nn = 0; nn < 2; ++nn) \
          acc[mt][nn] = __builtin_amdgcn_mfma_scale_f32_32x32x64_f8f6f4( \
              A_[mt], B_[nn], acc[mt][nn], 4, 4, 0, SCALE1, 0, SCALE1); }

// branchless e2m1 quantize: code = rint(min3(16|g|, 8|g|+2, 4|g|+4)) clamp 7, | sign
// C/D: col = lane&31, row = (r&3)+8*(r>>2)+4*hi [verified R2-R12]; nibble pack via shfl partner
#define EPI_FP4(BIAS, SC) \
    { float bvn[2]; \
      _Pragma("unroll") for (int nn = 0; nn < 2; ++nn) bvn[nn] = (BIAS)[w64 + (nn << 5) + l31]; \
      _Pragma("unroll") for (int mt = 0; mt < 2; ++mt) \
      _Pragma("unroll") for (int nn = 0; nn < 2; ++nn) \
      _Pragma("unroll") for (int r = 0; r < 16; ++r){ \
          int row = (mt << 5) + (r & 3) + ((r >> 2) << 3) + (hi << 2) + 2; \
          float g = gelu_fast(acc[mt][nn][r] * (SC) + bvn[nn]); \
          float ag = fabsf(g); \
          float f = fminf(fminf(16.0f * ag, fmaf(8.0f, ag, 2.0f)), fmaf(4.0f, ag, 4.0f)); \
          f = fminf(f, 7.0f); \
          int code = (int)rintf(f); \
          if (g < 0.0f) code |= 8; \
          int pcode = __shfl_xor(code, 1); \
          if (!(l31 & 1)) \
              ht4[row * HT4_S + ((w64 + (nn << 5) + l31) >> 1)] = (unsigned char)(code | (pcode << 4)); \
      } }

// fp4 layer: 20 K-steps of 64, fully unrolled, A/B ring-2, loads after use (1-step lead)
#define CONV_MX44(WQ) \
    { const unsigned char* bptr = (WQ) + (size_t)((w << 11) + lane * 16); \
      i32x8 Bf[2][2]; i32x8 Af[2][2]; \
      LOADB4(Bf[0], 0, bptr); LOADA4(Af[0], 0); \
      LOADB4(Bf[1], 1, bptr); LOADA4(Af[1], 1); \
      _Pragma("unroll") \
      for (int s = 0; s < 20; ++s){ \
          MFMX44(Af[s & 1], Bf[s & 1]); \
          if (s + 2 < 20){ LOADB4(Bf[s & 1], s + 2, bptr); LOADA4(Af[s & 1], s + 2); } \
      } }

    // ---- conv0 (bf16, 10 K-steps of 16, fully unrolled, ring-2) ----
    ZEROALL;
    {
        const unsigned short* b0ptr = wp0 + (size_t)((w << 10) + lane * 8);
        bf16x8 Bc[2][2]; bf16x8 Xc[2][2];
        LOADB0(Bc[0], 0); LOADAX(Xc[0], 0);
        LOADB0(Bc[1], 1); LOADAX(Xc[1], 1);
        #pragma unroll
        for (int s = 0; s < 10; ++s){
            MFX(Xc[s & 1], Bc[s & 1]);
            if (s + 2 < 10){ LOADB0(Bc[s & 1], s + 2); LOADAX(Xc[s & 1], s + 2); }
        }
    }
    EPI_FP4(B0, 1.0f);
    __syncthreads();

    // ---- conv1 (MX fp4 x fp4) ----
    ZEROALL;
    CONV_MX44(wq1);
    __syncthreads();
    EPI_FP4(B1, INV512);
    __syncthreads();

    // ---- conv2 (MX fp4 x fp4) + mean pool ----
    ZEROALL;
    CONV_MX44(wq2);
    {
        float bvn[2];
        #pragma unroll
        for (int nn = 0; nn < 2; ++nn) bvn[nn] = B2[w64 + (nn << 5) + l31];
        #pragma unroll
        for (int nn = 0; nn < 2; ++nn){
            float a = 0.f;
            #pragma unroll
            for (int mt = 0; mt < 2; ++mt)
                #pragma unroll
                for (int r = 0; r < 16; ++r)
                    a += gelu_fast(acc[mt][nn][r] * INV512 + bvn[nn]);
            a += __shfl_xor(a, 32);
            if (hi == 0)
                pooled[(size_t)b * 256 + w64 + (nn << 5) + l31] = f2bf(a * (1.0f / 64.0f));
        }
    }
}

// ---------------- Kernel 2a: heads stages A-C, 16 batches/block (R7/R10-proven) ----------------
#define AS 264

__global__ __launch_bounds__(256) void heads_a_kernel(
    const unsigned short* __restrict__ pooled,
    const float* __restrict__ proj_b, const float* __restrict__ val_b1,
    const float* __restrict__ pos_b1, const float* __restrict__ res_b1,
    const float* __restrict__ val_b2, const float* __restrict__ pos_b2,
    const float* __restrict__ mix_b,
    const unsigned short* __restrict__ pk,
    unsigned short* __restrict__ rh, float* __restrict__ meta,
    float* __restrict__ accums)
{
    __shared__ unsigned short pb [16 * AS];
    __shared__ unsigned short eb [16 * AS];
    __shared__ unsigned short vb [16 * AS];
    __shared__ unsigned short phb[16 * AS];
    __shared__ unsigned short rhb[16 * AS];
    __shared__ float av [16 * 132];
    __shared__ float avs[16 * 132];
    __shared__ float psort[16][4];
    __shared__ int   rank [16][4];
    __shared__ float qsh  [16][2];
    __shared__ float mlsh [16][2];
    __shared__ float sposh[16][4];

    const int tid  = threadIdx.x;
    const int b0   = blockIdx.x * 16;
    const int w    = tid >> 6;
    const int lane = tid & 63;
    const int l15  = lane & 15;
    const int q    = lane >> 4;
    const int q8   = q << 3;
    const int q4   = q << 2;

    {
        int g = tid >> 4, seg = tid & 15;
        const unsigned short* ps = pooled + ((size_t)(b0 + g) << 8) + (seg << 4);
        bf16x8 a0 = *(const bf16x8*)ps;
        bf16x8 a1 = *(const bf16x8*)(ps + 8);
        *(bf16x8*)&pb[g * AS + (seg << 4)]     = a0;
        *(bf16x8*)&pb[g * AS + (seg << 4) + 8] = a1;
    }
    __syncthreads();

#define HGEMM256(ASRC, GOFF, BIAS, DST) \
    { f32x4 hacc[4]; \
      _Pragma("unroll") for (int nt = 0; nt < 4; ++nt) hacc[nt] = (f32x4){0.f,0.f,0.f,0.f}; \
      _Pragma("unroll") for (int kk = 0; kk < 8; ++kk){ \
          bf16x8 af = *(const bf16x8*)&(ASRC)[l15 * AS + (kk << 5) + q8]; \
          _Pragma("unroll") for (int nt = 0; nt < 4; ++nt){ \
              bf16x8 bfr = *(const bf16x8*)(pk + (GOFF) + (size_t)((((kk << 4) + (w << 2) + nt) << 6) + lane) * 8); \
              hacc[nt] = __builtin_amdgcn_mfma_f32_16x16x32_bf16(af, bfr, hacc[nt], 0, 0, 0); } } \
      _Pragma("unroll") for (int nt = 0; nt < 4; ++nt){ \
          int n = (w << 6) + (nt << 4) + l15; \
          float bv = (BIAS)[n]; \
          _Pragma("unroll") for (int r = 0; r < 4; ++r) \
              (DST)[(q4 + r) * AS + n] = f2bf(gelu_fast(hacc[nt][r] + bv)); } }

    HGEMM256(pb, O_PROJ, proj_b, eb);
    __syncthreads();

    HGEMM256(eb, O_VAL1, val_b1, vb);
    HGEMM256(eb, O_POS1, pos_b1, phb);
    HGEMM256(eb, O_RES1, res_b1, rhb);
    __syncthreads();

    {
        f32x4 acc2[2];
        #pragma unroll
        for (int nt = 0; nt < 2; ++nt) acc2[nt] = (f32x4){0.f,0.f,0.f,0.f};
        #pragma unroll
        for (int kk = 0; kk < 8; ++kk){
            bf16x8 af = *(const bf16x8*)&vb[l15 * AS + (kk << 5) + q8];
            #pragma unroll
            for (int nt = 0; nt < 2; ++nt){
                bf16x8 bfr = *(const bf16x8*)(pk + O_VAL2 + (size_t)(((kk*8 + w*2 + nt) << 6) + lane) * 8);
                acc2[nt] = __builtin_amdgcn_mfma_f32_16x16x32_bf16(af, bfr, acc2[nt], 0, 0, 0);
            }
        }
        #pragma unroll
        for (int nt = 0; nt < 2; ++nt){
            int j = (w << 5) + (nt << 4) + l15;
            float bv = val_b2[j];
            #pragma unroll
            for (int r = 0; r < 4; ++r)
                av[(q4 + r) * 132 + j] = acc2[nt][r] + bv;
        }
    }
    if (w == 0){
        f32x4 accp = (f32x4){0.f,0.f,0.f,0.f};
        #pragma unroll
        for (int kk = 0; kk < 8; ++kk){
            bf16x8 af  = *(const bf16x8*)&phb[l15 * AS + (kk << 5) + q8];
            bf16x8 bfr = *(const bf16x8*)(pk + O_POS2 + (size_t)((kk << 6) + lane) * 8);
            accp = __builtin_amdgcn_mfma_f32_16x16x32_bf16(af, bfr, accp, 0, 0, 0);
        }
        if (l15 < 4){
            float bv = pos_b2[l15];
            #pragma unroll
            for (int r = 0; r < 4; ++r){
                float raw = accp[r] + bv;
                sposh[q4 + r][l15] = 63.0f * __builtin_amdgcn_rcpf(1.0f + __expf(-raw));
            }
        }
    } else if (w == 1){
        f32x4 accm = (f32x4){0.f,0.f,0.f,0.f};
        #pragma unroll
        for (int kk = 0; kk < 8; ++kk){
            bf16x8 af  = *(const bf16x8*)&eb[l15 * AS + (kk << 5) + q8];
            bf16x8 bfr = *(const bf16x8*)(pk + O_MIX + (size_t)((kk << 6) + lane) * 8);
            accm = __builtin_amdgcn_mfma_f32_16x16x32_bf16(af, bfr, accm, 0, 0, 0);
        }
        if (l15 < 2){
            #pragma unroll
            for (int r = 0; r < 4; ++r)
                mlsh[q4 + r][l15] = accm[r] + mix_b[l15];
        }
    }
    __syncthreads();

    if (tid < 16){
        int g = tid;
        float sv[4] = { sposh[g][0], sposh[g][1], sposh[g][2], sposh[g][3] };
        #pragma unroll
        for (int i = 0; i < 4; ++i){
            int r = 0;
            #pragma unroll
            for (int jj = 0; jj < 4; ++jj){
                r += (sv[jj] < sv[i]) ? 1 : 0;
                if (jj < i) r += (sv[jj] == sv[i]) ? 1 : 0;
            }
            rank[g][i] = r;
            psort[g][r] = sv[i];
        }
        psort[g][0] = 0.0f; psort[g][3] = 63.0f;
        float p1 = psort[g][1], p2 = psort[g][2];
        float g1 = p1, g2 = p2 - p1, g3 = 63.0f - p2;
        const float MG = 10.5f;
        float r1 = fmaxf(MG - g1, 0.f), r2 = fmaxf(MG - g2, 0.f), r3 = fmaxf(MG - g3, 0.f);
        float sp = (r1*r1 + r2*r2 + r3*r3) * (1.0f / 3.0f);
        float l0 = mlsh[g][0], l1 = mlsh[g][1];
        float m = fmaxf(l0, l1);
        float e0 = __expf(l0 - m), e1 = __expf(l1 - m);
        float inv = 1.0f / (e0 + e1);
        float q0 = e0 * inv, q1 = e1 * inv;
        qsh[g][0] = q0; qsh[g][1] = q1;
        float entc = q0 * logf(q0 + 1e-8f) + q1 * logf(q1 + 1e-8f);
        atomicAdd(&accums[2], entc);
        atomicAdd(&accums[3], q0);
        atomicAdd(&accums[4], q1);
        atomicAdd(&accums[5], sp);
    }
    __syncthreads();

    #pragma unroll
    for (int u2 = 0; u2 < 8; ++u2){
        int idx2 = tid * 8 + u2;
        int g = idx2 >> 7, j = idx2 & 127;
        avs[g * 132 + rank[g][j >> 5] * 32 + (j & 31)] = av[g * 132 + j];
    }
    __syncthreads();

    {
        int g = tid >> 4, c16 = (tid & 15) << 4;
        bf16x8 a0 = *(const bf16x8*)&rhb[g * AS + c16];
        bf16x8 a1 = *(const bf16x8*)&rhb[g * AS + c16 + 8];
        unsigned short* dst = rh + ((size_t)(b0 + g) << 8) + c16;
        *(bf16x8*)dst       = a0;
        *(bf16x8*)(dst + 8) = a1;
    }
    if (tid < 132){
        for (int g = 0; g < 16; ++g){
            float v;
            if (tid < 128)       v = avs[g * 132 + tid];
            else if (tid == 128) v = psort[g][1];
            else if (tid == 129) v = psort[g][2];
            else if (tid == 130) v = qsh[g][0];
            else                 v = qsh[g][1];
            meta[(size_t)(b0 + g) * 132 + tid] = v;
        }
    }
}

// ---------------- Kernel 2b: residual GEMM + interp + recon/L1 losses ----------------
__global__ __launch_bounds__(256) void resid_loss_kernel(
    const float* __restrict__ A, const unsigned short* __restrict__ rh,
    const float* __restrict__ res_b2, const unsigned short* __restrict__ pk,
    const float* __restrict__ meta, float* __restrict__ accums)
{
    __shared__ float ml[16 * 132];
    __shared__ float wred[4], wred2[4];

    const int tid  = threadIdx.x;
    const int w    = tid >> 6;
    const int lane = tid & 63;
    const int l15  = lane & 15;
    const int q    = lane >> 4;
    const int q8   = q << 3;
    const int q4   = q << 2;
    const int bg   = blockIdx.x >> 2;
    const int cc   = blockIdx.x & 3;
    const int b0   = bg << 4;

    for (int i = tid; i < 16 * 132; i += 256)
        ml[i] = meta[(size_t)b0 * 132 + i];
    __syncthreads();

    f32x4 acc[8];
    #pragma unroll
    for (int nt = 0; nt < 8; ++nt) acc[nt] = (f32x4){0.f,0.f,0.f,0.f};
    #pragma unroll
    for (int kk = 0; kk < 8; ++kk){
        bf16x8 af = *(const bf16x8*)(rh + ((size_t)(b0 + l15) << 8) + (kk << 5) + q8);
        #pragma unroll
        for (int nt = 0; nt < 8; ++nt){
            int ntg = (cc << 5) + (w << 3) + nt;
            bf16x8 bfr = *(const bf16x8*)(pk + O_RES2 + (size_t)((kk << 7) + ntg) * 512 + (lane << 3));
            acc[nt] = __builtin_amdgcn_mfma_f32_16x16x32_bf16(af, bfr, acc[nt], 0, 0, 0);
        }
    }

    float lsq = 0.f, ll1 = 0.f;
    #pragma unroll
    for (int nt = 0; nt < 8; ++nt){
        int e = (cc << 9) + (w << 7) + (nt << 4) + l15;
        float rbv = res_b2[e];
        int t = e >> 5, d = e & 31;
        float tf = (float)t;
        #pragma unroll
        for (int r = 0; r < 4; ++r){
            int g = q4 + r;
            const float* mg = &ml[g * 132];
            float p1 = mg[128], p2 = mg[129], q0 = mg[130], q1 = mg[131];
            float res = acc[nt][r] + rbv;
            int cnt = (p1 <= tf) + (p2 <= tf) + (tf >= 63.0f);
            int idx = cnt < 2 ? cnt : 2;
            float left  = idx == 0 ? 0.0f : (idx == 1 ? p1 : p2);
            float right = idx == 0 ? p1   : (idx == 1 ? p2 : 63.0f);
            float wgt = (tf - left) / (right - left + 1e-8f);
            wgt = fminf(fmaxf(wgt, 0.f), 1.f);
            float vl = mg[idx * 32 + d];
            float vr = mg[idx * 32 + 32 + d];
            float coarse = vl + wgt * (vr - vl);
            float a = A[((size_t)(b0 + g) << 11) + e];
            float fine = coarse + res;
            float recon = q0 * coarse + q1 * fine;
            float dd = recon - a;
            lsq += dd * dd;
            ll1 += fabsf(res);
        }
    }
    #pragma unroll
    for (int off = 32; off > 0; off >>= 1){
        lsq += __shfl_down(lsq, off);
        ll1 += __shfl_down(ll1, off);
    }
    if (lane == 0){ wred[w] = lsq; wred2[w] = ll1; }
    __syncthreads();
    if (tid == 0){
        atomicAdd(&accums[0], wred[0] + wred[1] + wred[2] + wred[3]);
        atomicAdd(&accums[1], wred2[0] + wred2[1] + wred2[2] + wred2[3]);
    }
}

// ---------------- Kernel 3: finalize ----------------
__global__ void finalize_kernel(const float* __restrict__ accums, float* __restrict__ out){
    float rs = accums[0], l1s = accums[1], ents = accums[2];
    float q0s = accums[3], q1s = accums[4], sps = accums[5];
    const float invN = 1.0f / (4096.0f * 2048.0f);
    const float invB = 1.0f / 4096.0f;
    float recon_loss = rs * invN;
    float l1   = l1s * invN;
    float ent  = -ents * invB;
    float mq0  = q0s * invB - 0.5f, mq1 = q1s * invB - 0.5f;
    float balance = mq0*mq0 + mq1*mq1;
    float spacing = sps * invB;
    out[0] = recon_loss + 0.05f*l1 + 0.01f*ent + 0.1f*balance + 0.1f*spacing;
}

extern "C" void kernel_launch(void* const* d_in, const int* in_sizes, int n_in,
                              void* d_out, int out_size, void* d_ws, size_t ws_size,
                              hipStream_t stream)
{
    const float* A      = (const float*)d_in[0];
    const float* W0     = (const float*)d_in[1];
    const float* B0     = (const float*)d_in[2];
    const float* W1     = (const float*)d_in[3];
    const float* B1     = (const float*)d_in[4];
    const float* W2     = (const float*)d_in[5];
    const float* B2     = (const float*)d_in[6];
    const float* proj_w = (const float*)d_in[7];
    const float* proj_b = (const float*)d_in[8];
    const float* val_w1 = (const float*)d_in[9];
    const float* val_b1 = (const float*)d_in[10];
    const float* val_w2 = (const float*)d_in[11];
    const float* val_b2 = (const float*)d_in[12];
    const float* pos_w1 = (const float*)d_in[13];
    const float* pos_b1 = (const float*)d_in[14];
    const float* pos_w2 = (const float*)d_in[15];
    const float* pos_b2 = (const float*)d_in[16];
    const float* res_w1 = (const float*)d_in[17];
    const float* res_b1 = (const float*)d_in[18];
    const float* res_w2 = (const float*)d_in[19];
    const float* res_b2 = (const float*)d_in[20];
    const float* mix_w  = (const float*)d_in[21];
    const float* mix_b  = (const float*)d_in[22];

    char* wsb = (char*)d_ws;
    float* accums = (float*)wsb;
    unsigned short* pooled = (unsigned short*)(wsb + 256);
    unsigned short* pkbuf  = (unsigned short*)(wsb + 256 + 2097152);
    unsigned short* rhbuf  = (unsigned short*)(wsb + 256 + 2097152 + (size_t)PK_TOTAL * 2);
    float* metabuf = (float*)(wsb + 256 + 2097152 + (size_t)PK_TOTAL * 2 + 2097152);
    unsigned char* wq1 = (unsigned char*)(wsb + 256 + 2097152 + (size_t)PK_TOTAL * 2 + 2097152
                                          + (size_t)4096 * 132 * 4);
    unsigned char* wq2 = wq1 + WQ4_BYTES;

    hipMemsetAsync(accums, 0, 64 * sizeof(float), stream);

    hipLaunchKernelGGL(pack_weights, dim3((PK_TOTAL + 255) / 256), dim3(256), 0, stream,
                       W0, W1, W2, proj_w, val_w1, pos_w1, res_w1,
                       val_w2, res_w2, pos_w2, mix_w, pkbuf, wq1, wq2);

    hipLaunchKernelGGL(conv_mfma_kernel, dim3(NB), dim3(256), 0, stream,
                       A, B0, B1, B2,
                       pkbuf + O_WP0, wq1, wq2, pooled);

    hipLaunchKernelGGL(heads_a_kernel, dim3(NB / 16), dim3(256), 0, stream,
                       pooled, proj_b, val_b1, pos_b1, res_b1, val_b2, pos_b2, mix_b,
                       pkbuf, rhbuf, metabuf, accums);

    hipLaunchKernelGGL(resid_loss_kernel, dim3(NB / 16 * 4), dim3(256), 0, stream,
                       A, rhbuf, res_b2, pkbuf, metabuf, accums);

    hipLaunchKernelGGL(finalize_kernel, dim3(1), dim3(1), 0, stream,
                       accums, (float*)d_out);
}

// Round 14
// 737.501 us; speedup vs baseline: 1.0536x; 1.0536x over previous
//
#include <hip/hip_runtime.h>

#define NB 4096

typedef __attribute__((ext_vector_type(8)))  __bf16 bf16x8;
typedef __attribute__((ext_vector_type(4)))  float  f32x4;
typedef __attribute__((ext_vector_type(16))) float  f32x16;
typedef __attribute__((ext_vector_type(8)))  int    i32x8;
typedef __attribute__((ext_vector_type(4)))  int    i32x4;

// gelu tanh-approx via sigmoid identity: x * rcp(1 + exp(-2y)), y = x(c0 + c1 x^2)
__device__ __forceinline__ float gelu_fast(float x){
    float x2 = x * x;
    float z  = x * (-1.59576912f - 0.07135482f * x2);   // -2y
    float e  = __expf(z);
    return x * __builtin_amdgcn_rcpf(1.0f + e);
}
__device__ __forceinline__ unsigned short f2bf(float x){
    unsigned b = __float_as_uint(x);
    b += 0x7fffu + ((b >> 16) & 1u);
    return (unsigned short)(b >> 16);
}
// e2m1 fp4 code: values {0,0.5,1,1.5,2,3,4,6} = codes 0..7, sign bit 3.
__device__ __forceinline__ unsigned f2fp4(float x){
    unsigned s = (__float_as_uint(x) >> 31) & 1u;
    float m = fabsf(x);
    int c;
    if      (m < 0.25f) c = 0;
    else if (m < 0.75f) c = 1;
    else if (m < 1.25f) c = 2;
    else if (m < 1.75f) c = 3;
    else if (m < 2.5f)  c = 4;
    else if (m < 3.5f)  c = 5;
    else if (m < 5.0f)  c = 6;
    else                c = 7;
    return (s << 3) | (unsigned)c;
}

// ---------------- pack offsets (elements) ----------------
#define O_WP0  0
#define O_WP1  40960
#define O_WP2  368640
#define O_PROJ 696320
#define O_VAL1 761856
#define O_POS1 827392
#define O_RES1 892928
#define O_VAL2 958464
#define O_RES2 991232
#define O_POS2 1515520
#define O_MIX  1519616
#define PK_TOTAL 1523712

#define WQ4_BYTES 163840   // 256*1280 fp4 nibbles per conv layer

__device__ __forceinline__ unsigned short pack_std_elem(const float* W, int N, int t){
    int j = t & 7, lane = (t >> 3) & 63, rest = t >> 9;
    int ntcnt = N >> 4;
    int nt = rest % ntcnt, kk = rest / ntcnt;
    int n = nt*16 + (lane & 15), k = kk*32 + ((lane >> 4) << 3) + j;
    return f2bf(W[k * N + n]);
}
__device__ __forceinline__ unsigned short pack_pad_elem(const float* W, int Nreal, int t){
    int j = t & 7, lane = (t >> 3) & 63, kk = t >> 9;
    int n = lane & 15, k = kk*32 + ((lane >> 4) << 3) + j;
    return (n < Nreal) ? f2bf(W[k * Nreal + n]) : (unsigned short)0;
}
// fp4 conv pack for mfma_scale 32x32x64 (fmt=4): per lane 32 k-elems = 16 B, LSB-first.
__device__ __forceinline__ unsigned char pack_fp4_byte(const float* W, int t){
    int byt = t & 15, lane = (t >> 4) & 63, g = (t >> 10) & 7, S = t >> 13;
    int n = g*32 + (lane & 31);
    int kbase = S*64 + ((lane >> 5) << 5) + (byt << 1);
    int k0 = kbase, k1 = kbase + 1;
    float v0 = W[n*1280 + (k0 & 255)*5 + (k0 >> 8)] * 64.0f;
    float v1 = W[n*1280 + (k1 & 255)*5 + (k1 >> 8)] * 64.0f;
    return (unsigned char)(f2fp4(v0) | (f2fp4(v1) << 4));
}

__global__ __launch_bounds__(256) void pack_weights(
    const float* __restrict__ W0, const float* __restrict__ W1, const float* __restrict__ W2,
    const float* __restrict__ proj_w, const float* __restrict__ val_w1,
    const float* __restrict__ pos_w1, const float* __restrict__ res_w1,
    const float* __restrict__ val_w2, const float* __restrict__ res_w2,
    const float* __restrict__ pos_w2, const float* __restrict__ mix_w,
    unsigned short* __restrict__ pk,
    unsigned char* __restrict__ wq1, unsigned char* __restrict__ wq2)
{
    int idx = blockIdx.x * 256 + threadIdx.x;
    if (idx >= PK_TOTAL) return;
    if (idx < O_WP1){
        int t = idx;
        int j = t & 7, lane = (t >> 3) & 63, nt = (t >> 9) & 7, s = t >> 12;   // s 0..9
        int co = nt*32 + (lane & 31);
        int tap = s >> 1, ci = ((s & 1) << 4) + ((lane >> 5) << 3) + j;
        pk[idx] = f2bf(W0[co*160 + ci*5 + tap]);
    } else if (idx < O_WP1 + WQ4_BYTES){
        wq1[idx - O_WP1] = pack_fp4_byte(W1, idx - O_WP1);
    } else if (idx < O_WP2){
        // gap
    } else if (idx < O_WP2 + WQ4_BYTES){
        wq2[idx - O_WP2] = pack_fp4_byte(W2, idx - O_WP2);
    } else if (idx < O_PROJ){
        // gap
    }
    else if (idx < O_VAL1) pk[idx] = pack_std_elem(proj_w, 256, idx - O_PROJ);
    else if (idx < O_POS1) pk[idx] = pack_std_elem(val_w1, 256, idx - O_VAL1);
    else if (idx < O_RES1) pk[idx] = pack_std_elem(pos_w1, 256, idx - O_POS1);
    else if (idx < O_VAL2) pk[idx] = pack_std_elem(res_w1, 256, idx - O_RES1);
    else if (idx < O_RES2) pk[idx] = pack_std_elem(val_w2, 128, idx - O_VAL2);
    else if (idx < O_POS2) pk[idx] = pack_std_elem(res_w2, 2048, idx - O_RES2);
    else if (idx < O_MIX)  pk[idx] = pack_pad_elem(pos_w2, 4, idx - O_POS2);
    else                   pk[idx] = pack_pad_elem(mix_w, 2, idx - O_MIX);
}

// ---------------- Kernel 1: MX fp4 x fp4 conv, 256 thr, 1 batch/block ----------------
// R12/R13 design (correctness-verified) with NAMED-REGISTER rings: no ext_vector
// arrays in the K-loop at all -> register allocation independent of unroll
// heuristics (rule #20: runtime-indexed vector arrays go to scratch).
#define HT4_S 136
#define XT_S 40
#define INV512 0.001953125f
#define SCALE1 0x7F

__global__ __launch_bounds__(256, 4) void conv_mfma_kernel(
    const float* __restrict__ A,
    const float* __restrict__ B0, const float* __restrict__ B1, const float* __restrict__ B2,
    const unsigned short* __restrict__ wp0,
    const unsigned char* __restrict__ wq1, const unsigned char* __restrict__ wq2,
    unsigned short* __restrict__ pooled)
{
    __shared__ __align__(16) unsigned short xt[68 * XT_S];
    __shared__ __align__(16) unsigned char  ht4[68 * HT4_S];

    const int tid  = threadIdx.x;
    const int b    = blockIdx.x;
    const int w    = tid >> 6;        // 0..3: 64-col output group
    const int lane = tid & 63;
    const int l31  = lane & 31;
    const int hi   = lane >> 5;
    const int hi8  = hi << 3;
    const int w64  = w << 6;

    // zero halo rows (taps reach rows 0,1,66,67)
    for (int i = tid; i < 4 * HT4_S; i += 256){
        int r = i / HT4_S, c = i - r * HT4_S;
        int rr = (r < 2 ? r : r + 64);
        ht4[rr * HT4_S + c] = 0;
    }
    if (tid < 128){
        int r = tid >> 5, c = tid & 31;
        int rr = (r < 2 ? r : r + 64);
        xt[rr * XT_S + c] = 0;
    }
    // pack input: 256 threads cover the batch (256*8 = 2048 elems)
    {
        const float* Ab = A + (size_t)b * 2048;
        int e0 = tid << 3;
        int t = e0 >> 5, c = e0 & 31;
        const float4* p = (const float4*)(Ab + e0);
        float4 v0 = p[0], v1 = p[1];
        union { unsigned short u[8]; bf16x8 v; } pkv;
        pkv.u[0]=f2bf(v0.x); pkv.u[1]=f2bf(v0.y); pkv.u[2]=f2bf(v0.z); pkv.u[3]=f2bf(v0.w);
        pkv.u[4]=f2bf(v1.x); pkv.u[5]=f2bf(v1.y); pkv.u[6]=f2bf(v1.z); pkv.u[7]=f2bf(v1.w);
        *(bf16x8*)&xt[(t + 2) * XT_S + c] = pkv.v;
    }
    __syncthreads();

    f32x16 acc[2][2];   // [mt][nn] — all references lexically constant-indexed

#define ZEROALL \
    { _Pragma("unroll") for (int mt = 0; mt < 2; ++mt) \
      _Pragma("unroll") for (int nn = 0; nn < 2; ++nn) \
      _Pragma("unroll") for (int r = 0; r < 16; ++r) acc[mt][nn][r] = 0.f; }

// ----- bf16 conv0 pieces (named regs); fragment indexing verified R2-R13 -----
#define LAX(D0, D1, S) { \
    D0 = *(const bf16x8*)&xt[(l31 + ((S) >> 1)) * XT_S + (((S) & 1) << 4) + hi8]; \
    D1 = *(const bf16x8*)&xt[(32 + l31 + ((S) >> 1)) * XT_S + (((S) & 1) << 4) + hi8]; }
#define LB0(D0, D1, S) { \
    D0 = *(const bf16x8*)(b0ptr + (size_t)(S) * 4096); \
    D1 = *(const bf16x8*)(b0ptr + (size_t)(S) * 4096 + 512); }
#define MFX4(XA0, XA1, BB0, BB1) { \
    acc[0][0] = __builtin_amdgcn_mfma_f32_32x32x16_bf16(XA0, BB0, acc[0][0], 0, 0, 0); \
    acc[0][1] = __builtin_amdgcn_mfma_f32_32x32x16_bf16(XA0, BB1, acc[0][1], 0, 0, 0); \
    acc[1][0] = __builtin_amdgcn_mfma_f32_32x32x16_bf16(XA1, BB0, acc[1][0], 0, 0, 0); \
    acc[1][1] = __builtin_amdgcn_mfma_f32_32x32x16_bf16(XA1, BB1, acc[1][1], 0, 0, 0); }

// ----- MX fp4 pieces (named regs); layouts verified R12/R13 -----
#define ZERO4 ((i32x4){0,0,0,0})
#define WIDEN(T_) __builtin_shufflevector((T_), ZERO4, 0, 1, 2, 3, 4, 5, 6, 7)
// A: row = mt*32 + l31 + tap(S>>2); byte off = (S&3)*32 + hi*16 (16 contig bytes = 32 chans)
#define LA4(D0, D1, S) { \
    i32x4 t0_ = *(const i32x4*)&ht4[(l31 + ((S) >> 2)) * HT4_S + (((S) & 3) << 5) + (hi << 4)]; \
    i32x4 t1_ = *(const i32x4*)&ht4[(32 + l31 + ((S) >> 2)) * HT4_S + (((S) & 3) << 5) + (hi << 4)]; \
    D0 = WIDEN(t0_); D1 = WIDEN(t1_); }
#define LB4(D0, D1, S) { \
    i32x4 t0_ = *(const i32x4*)(bptr + (size_t)(S) * 8192); \
    i32x4 t1_ = *(const i32x4*)(bptr + (size_t)(S) * 8192 + 1024); \
    D0 = WIDEN(t0_); D1 = WIDEN(t1_); }
#define MF44(A0_, A1_, B0_, B1_) { \
    acc[0][0] = __builtin_amdgcn_mfma_scale_f32_32x32x64_f8f6f4(A0_, B0_, acc[0][0], 4, 4, 0, SCALE1, 0, SCALE1); \
    acc[0][1] = __builtin_amdgcn_mfma_scale_f32_32x32x64_f8f6f4(A0_, B1_, acc[0][1], 4, 4, 0, SCALE1, 0, SCALE1); \
    acc[1][0] = __builtin_amdgcn_mfma_scale_f32_32x32x64_f8f6f4(A1_, B0_, acc[1][0], 4, 4, 0, SCALE1, 0, SCALE1); \
    acc[1][1] = __builtin_amdgcn_mfma_scale_f32_32x32x64_f8f6f4(A1_, B1_, acc[1][1], 4, 4, 0, SCALE1, 0, SCALE1); }

// branchless e2m1 quantize: code = rint(min3(16|g|, 8|g|+2, 4|g|+4)) clamp 7, | sign
// C/D: col = lane&31, row = (r&3)+8*(r>>2)+4*hi [verified R2-R13]; nibble pack via shfl partner
#define EPI_FP4(BIAS, SC) \
    { float bvn[2]; \
      _Pragma("unroll") for (int nn = 0; nn < 2; ++nn) bvn[nn] = (BIAS)[w64 + (nn << 5) + l31]; \
      _Pragma("unroll") for (int mt = 0; mt < 2; ++mt) \
      _Pragma("unroll") for (int nn = 0; nn < 2; ++nn) \
      _Pragma("unroll") for (int r = 0; r < 16; ++r){ \
          int row = (mt << 5) + (r & 3) + ((r >> 2) << 3) + (hi << 2) + 2; \
          float g = gelu_fast(acc[mt][nn][r] * (SC) + bvn[nn]); \
          float ag = fabsf(g); \
          float f = fminf(fminf(16.0f * ag, fmaf(8.0f, ag, 2.0f)), fmaf(4.0f, ag, 4.0f)); \
          f = fminf(f, 7.0f); \
          int code = (int)rintf(f); \
          if (g < 0.0f) code |= 8; \
          int pcode = __shfl_xor(code, 1); \
          if (!(l31 & 1)) \
              ht4[row * HT4_S + ((w64 + (nn << 5) + l31) >> 1)] = (unsigned char)(code | (pcode << 4)); \
      } }

// fp4 layer: 20 K-steps of 64, 2 steps/iter, named rings (no vector arrays)
#define CONV_MX44(WQ) \
    { const unsigned char* bptr = (WQ) + (size_t)((w << 11) + lane * 16); \
      i32x8 Aa0, Aa1, Ab0, Ab1, Ba0, Ba1, Bb0, Bb1; \
      LB4(Ba0, Ba1, 0); LA4(Aa0, Aa1, 0); \
      LB4(Bb0, Bb1, 1); LA4(Ab0, Ab1, 1); \
      _Pragma("unroll") \
      for (int s = 0; s < 20; s += 2){ \
          MF44(Aa0, Aa1, Ba0, Ba1); \
          if (s + 2 < 20){ LB4(Ba0, Ba1, s + 2); LA4(Aa0, Aa1, s + 2); } \
          MF44(Ab0, Ab1, Bb0, Bb1); \
          if (s + 3 < 20){ LB4(Bb0, Bb1, s + 3); LA4(Ab0, Ab1, s + 3); } \
      } }

    // ---- conv0 (bf16, 10 K-steps of 16, named rings) ----
    ZEROALL;
    {
        const unsigned short* b0ptr = wp0 + (size_t)((w << 10) + lane * 8);
        bf16x8 Xa0, Xa1, Xb0, Xb1, Ba0, Ba1, Bb0, Bb1;
        LB0(Ba0, Ba1, 0); LAX(Xa0, Xa1, 0);
        LB0(Bb0, Bb1, 1); LAX(Xb0, Xb1, 1);
        #pragma unroll
        for (int s = 0; s < 10; s += 2){
            MFX4(Xa0, Xa1, Ba0, Ba1);
            if (s + 2 < 10){ LB0(Ba0, Ba1, s + 2); LAX(Xa0, Xa1, s + 2); }
            MFX4(Xb0, Xb1, Bb0, Bb1);
            if (s + 3 < 10){ LB0(Bb0, Bb1, s + 3); LAX(Xb0, Xb1, s + 3); }
        }
    }
    EPI_FP4(B0, 1.0f);
    __syncthreads();

    // ---- conv1 (MX fp4 x fp4) ----
    ZEROALL;
    CONV_MX44(wq1);
    __syncthreads();
    EPI_FP4(B1, INV512);
    __syncthreads();

    // ---- conv2 (MX fp4 x fp4) + mean pool ----
    ZEROALL;
    CONV_MX44(wq2);
    {
        float bvn[2];
        #pragma unroll
        for (int nn = 0; nn < 2; ++nn) bvn[nn] = B2[w64 + (nn << 5) + l31];
        #pragma unroll
        for (int nn = 0; nn < 2; ++nn){
            float a = 0.f;
            #pragma unroll
            for (int mt = 0; mt < 2; ++mt)
                #pragma unroll
                for (int r = 0; r < 16; ++r)
                    a += gelu_fast(acc[mt][nn][r] * INV512 + bvn[nn]);
            a += __shfl_xor(a, 32);
            if (hi == 0)
                pooled[(size_t)b * 256 + w64 + (nn << 5) + l31] = f2bf(a * (1.0f / 64.0f));
        }
    }
}

// ---------------- Kernel 2a: heads stages A-C, 16 batches/block (R7/R10-proven) ----------------
#define AS 264

__global__ __launch_bounds__(256) void heads_a_kernel(
    const unsigned short* __restrict__ pooled,
    const float* __restrict__ proj_b, const float* __restrict__ val_b1,
    const float* __restrict__ pos_b1, const float* __restrict__ res_b1,
    const float* __restrict__ val_b2, const float* __restrict__ pos_b2,
    const float* __restrict__ mix_b,
    const unsigned short* __restrict__ pk,
    unsigned short* __restrict__ rh, float* __restrict__ meta,
    float* __restrict__ accums)
{
    __shared__ unsigned short pb [16 * AS];
    __shared__ unsigned short eb [16 * AS];
    __shared__ unsigned short vb [16 * AS];
    __shared__ unsigned short phb[16 * AS];
    __shared__ unsigned short rhb[16 * AS];
    __shared__ float av [16 * 132];
    __shared__ float avs[16 * 132];
    __shared__ float psort[16][4];
    __shared__ int   rank [16][4];
    __shared__ float qsh  [16][2];
    __shared__ float mlsh [16][2];
    __shared__ float sposh[16][4];

    const int tid  = threadIdx.x;
    const int b0   = blockIdx.x * 16;
    const int w    = tid >> 6;
    const int lane = tid & 63;
    const int l15  = lane & 15;
    const int q    = lane >> 4;
    const int q8   = q << 3;
    const int q4   = q << 2;

    {
        int g = tid >> 4, seg = tid & 15;
        const unsigned short* ps = pooled + ((size_t)(b0 + g) << 8) + (seg << 4);
        bf16x8 a0 = *(const bf16x8*)ps;
        bf16x8 a1 = *(const bf16x8*)(ps + 8);
        *(bf16x8*)&pb[g * AS + (seg << 4)]     = a0;
        *(bf16x8*)&pb[g * AS + (seg << 4) + 8] = a1;
    }
    __syncthreads();

#define HGEMM256(ASRC, GOFF, BIAS, DST) \
    { f32x4 hacc[4]; \
      _Pragma("unroll") for (int nt = 0; nt < 4; ++nt) hacc[nt] = (f32x4){0.f,0.f,0.f,0.f}; \
      _Pragma("unroll") for (int kk = 0; kk < 8; ++kk){ \
          bf16x8 af = *(const bf16x8*)&(ASRC)[l15 * AS + (kk << 5) + q8]; \
          _Pragma("unroll") for (int nt = 0; nt < 4; ++nt){ \
              bf16x8 bfr = *(const bf16x8*)(pk + (GOFF) + (size_t)((((kk << 4) + (w << 2) + nt) << 6) + lane) * 8); \
              hacc[nt] = __builtin_amdgcn_mfma_f32_16x16x32_bf16(af, bfr, hacc[nt], 0, 0, 0); } } \
      _Pragma("unroll") for (int nt = 0; nt < 4; ++nt){ \
          int n = (w << 6) + (nt << 4) + l15; \
          float bv = (BIAS)[n]; \
          _Pragma("unroll") for (int r = 0; r < 4; ++r) \
              (DST)[(q4 + r) * AS + n] = f2bf(gelu_fast(hacc[nt][r] + bv)); } }

    HGEMM256(pb, O_PROJ, proj_b, eb);
    __syncthreads();

    HGEMM256(eb, O_VAL1, val_b1, vb);
    HGEMM256(eb, O_POS1, pos_b1, phb);
    HGEMM256(eb, O_RES1, res_b1, rhb);
    __syncthreads();

    {
        f32x4 acc2[2];
        #pragma unroll
        for (int nt = 0; nt < 2; ++nt) acc2[nt] = (f32x4){0.f,0.f,0.f,0.f};
        #pragma unroll
        for (int kk = 0; kk < 8; ++kk){
            bf16x8 af = *(const bf16x8*)&vb[l15 * AS + (kk << 5) + q8];
            #pragma unroll
            for (int nt = 0; nt < 2; ++nt){
                bf16x8 bfr = *(const bf16x8*)(pk + O_VAL2 + (size_t)(((kk*8 + w*2 + nt) << 6) + lane) * 8);
                acc2[nt] = __builtin_amdgcn_mfma_f32_16x16x32_bf16(af, bfr, acc2[nt], 0, 0, 0);
            }
        }
        #pragma unroll
        for (int nt = 0; nt < 2; ++nt){
            int j = (w << 5) + (nt << 4) + l15;
            float bv = val_b2[j];
            #pragma unroll
            for (int r = 0; r < 4; ++r)
                av[(q4 + r) * 132 + j] = acc2[nt][r] + bv;
        }
    }
    if (w == 0){
        f32x4 accp = (f32x4){0.f,0.f,0.f,0.f};
        #pragma unroll
        for (int kk = 0; kk < 8; ++kk){
            bf16x8 af  = *(const bf16x8*)&phb[l15 * AS + (kk << 5) + q8];
            bf16x8 bfr = *(const bf16x8*)(pk + O_POS2 + (size_t)((kk << 6) + lane) * 8);
            accp = __builtin_amdgcn_mfma_f32_16x16x32_bf16(af, bfr, accp, 0, 0, 0);
        }
        if (l15 < 4){
            float bv = pos_b2[l15];
            #pragma unroll
            for (int r = 0; r < 4; ++r){
                float raw = accp[r] + bv;
                sposh[q4 + r][l15] = 63.0f * __builtin_amdgcn_rcpf(1.0f + __expf(-raw));
            }
        }
    } else if (w == 1){
        f32x4 accm = (f32x4){0.f,0.f,0.f,0.f};
        #pragma unroll
        for (int kk = 0; kk < 8; ++kk){
            bf16x8 af  = *(const bf16x8*)&eb[l15 * AS + (kk << 5) + q8];
            bf16x8 bfr = *(const bf16x8*)(pk + O_MIX + (size_t)((kk << 6) + lane) * 8);
            accm = __builtin_amdgcn_mfma_f32_16x16x32_bf16(af, bfr, accm, 0, 0, 0);
        }
        if (l15 < 2){
            #pragma unroll
            for (int r = 0; r < 4; ++r)
                mlsh[q4 + r][l15] = accm[r] + mix_b[l15];
        }
    }
    __syncthreads();

    if (tid < 16){
        int g = tid;
        float sv[4] = { sposh[g][0], sposh[g][1], sposh[g][2], sposh[g][3] };
        #pragma unroll
        for (int i = 0; i < 4; ++i){
            int r = 0;
            #pragma unroll
            for (int jj = 0; jj < 4; ++jj){
                r += (sv[jj] < sv[i]) ? 1 : 0;
                if (jj < i) r += (sv[jj] == sv[i]) ? 1 : 0;
            }
            rank[g][i] = r;
            psort[g][r] = sv[i];
        }
        psort[g][0] = 0.0f; psort[g][3] = 63.0f;
        float p1 = psort[g][1], p2 = psort[g][2];
        float g1 = p1, g2 = p2 - p1, g3 = 63.0f - p2;
        const float MG = 10.5f;
        float r1 = fmaxf(MG - g1, 0.f), r2 = fmaxf(MG - g2, 0.f), r3 = fmaxf(MG - g3, 0.f);
        float sp = (r1*r1 + r2*r2 + r3*r3) * (1.0f / 3.0f);
        float l0 = mlsh[g][0], l1 = mlsh[g][1];
        float m = fmaxf(l0, l1);
        float e0 = __expf(l0 - m), e1 = __expf(l1 - m);
        float inv = 1.0f / (e0 + e1);
        float q0 = e0 * inv, q1 = e1 * inv;
        qsh[g][0] = q0; qsh[g][1] = q1;
        float entc = q0 * logf(q0 + 1e-8f) + q1 * logf(q1 + 1e-8f);
        atomicAdd(&accums[2], entc);
        atomicAdd(&accums[3], q0);
        atomicAdd(&accums[4], q1);
        atomicAdd(&accums[5], sp);
    }
    __syncthreads();

    #pragma unroll
    for (int u2 = 0; u2 < 8; ++u2){
        int idx2 = tid * 8 + u2;
        int g = idx2 >> 7, j = idx2 & 127;
        avs[g * 132 + rank[g][j >> 5] * 32 + (j & 31)] = av[g * 132 + j];
    }
    __syncthreads();

    {
        int g = tid >> 4, c16 = (tid & 15) << 4;
        bf16x8 a0 = *(const bf16x8*)&rhb[g * AS + c16];
        bf16x8 a1 = *(const bf16x8*)&rhb[g * AS + c16 + 8];
        unsigned short* dst = rh + ((size_t)(b0 + g) << 8) + c16;
        *(bf16x8*)dst       = a0;
        *(bf16x8*)(dst + 8) = a1;
    }
    if (tid < 132){
        for (int g = 0; g < 16; ++g){
            float v;
            if (tid < 128)       v = avs[g * 132 + tid];
            else if (tid == 128) v = psort[g][1];
            else if (tid == 129) v = psort[g][2];
            else if (tid == 130) v = qsh[g][0];
            else                 v = qsh[g][1];
            meta[(size_t)(b0 + g) * 132 + tid] = v;
        }
    }
}

// ---------------- Kernel 2b: residual GEMM + interp + recon/L1 losses ----------------
__global__ __launch_bounds__(256) void resid_loss_kernel(
    const float* __restrict__ A, const unsigned short* __restrict__ rh,
    const float* __restrict__ res_b2, const unsigned short* __restrict__ pk,
    const float* __restrict__ meta, float* __restrict__ accums)
{
    __shared__ float ml[16 * 132];
    __shared__ float wred[4], wred2[4];

    const int tid  = threadIdx.x;
    const int w    = tid >> 6;
    const int lane = tid & 63;
    const int l15  = lane & 15;
    const int q    = lane >> 4;
    const int q8   = q << 3;
    const int q4   = q << 2;
    const int bg   = blockIdx.x >> 2;
    const int cc   = blockIdx.x & 3;
    const int b0   = bg << 4;

    for (int i = tid; i < 16 * 132; i += 256)
        ml[i] = meta[(size_t)b0 * 132 + i];
    __syncthreads();

    f32x4 acc[8];
    #pragma unroll
    for (int nt = 0; nt < 8; ++nt) acc[nt] = (f32x4){0.f,0.f,0.f,0.f};
    #pragma unroll
    for (int kk = 0; kk < 8; ++kk){
        bf16x8 af = *(const bf16x8*)(rh + ((size_t)(b0 + l15) << 8) + (kk << 5) + q8);
        #pragma unroll
        for (int nt = 0; nt < 8; ++nt){
            int ntg = (cc << 5) + (w << 3) + nt;
            bf16x8 bfr = *(const bf16x8*)(pk + O_RES2 + (size_t)((kk << 7) + ntg) * 512 + (lane << 3));
            acc[nt] = __builtin_amdgcn_mfma_f32_16x16x32_bf16(af, bfr, acc[nt], 0, 0, 0);
        }
    }

    float lsq = 0.f, ll1 = 0.f;
    #pragma unroll
    for (int nt = 0; nt < 8; ++nt){
        int e = (cc << 9) + (w << 7) + (nt << 4) + l15;
        float rbv = res_b2[e];
        int t = e >> 5, d = e & 31;
        float tf = (float)t;
        #pragma unroll
        for (int r = 0; r < 4; ++r){
            int g = q4 + r;
            const float* mg = &ml[g * 132];
            float p1 = mg[128], p2 = mg[129], q0 = mg[130], q1 = mg[131];
            float res = acc[nt][r] + rbv;
            int cnt = (p1 <= tf) + (p2 <= tf) + (tf >= 63.0f);
            int idx = cnt < 2 ? cnt : 2;
            float left  = idx == 0 ? 0.0f : (idx == 1 ? p1 : p2);
            float right = idx == 0 ? p1   : (idx == 1 ? p2 : 63.0f);
            float wgt = (tf - left) / (right - left + 1e-8f);
            wgt = fminf(fmaxf(wgt, 0.f), 1.f);
            float vl = mg[idx * 32 + d];
            float vr = mg[idx * 32 + 32 + d];
            float coarse = vl + wgt * (vr - vl);
            float a = A[((size_t)(b0 + g) << 11) + e];
            float fine = coarse + res;
            float recon = q0 * coarse + q1 * fine;
            float dd = recon - a;
            lsq += dd * dd;
            ll1 += fabsf(res);
        }
    }
    #pragma unroll
    for (int off = 32; off > 0; off >>= 1){
        lsq += __shfl_down(lsq, off);
        ll1 += __shfl_down(ll1, off);
    }
    if (lane == 0){ wred[w] = lsq; wred2[w] = ll1; }
    __syncthreads();
    if (tid == 0){
        atomicAdd(&accums[0], wred[0] + wred[1] + wred[2] + wred[3]);
        atomicAdd(&accums[1], wred2[0] + wred2[1] + wred2[2] + wred2[3]);
    }
}

// ---------------- Kernel 3: finalize ----------------
__global__ void finalize_kernel(const float* __restrict__ accums, float* __restrict__ out){
    float rs = accums[0], l1s = accums[1], ents = accums[2];
    float q0s = accums[3], q1s = accums[4], sps = accums[5];
    const float invN = 1.0f / (4096.0f * 2048.0f);
    const float invB = 1.0f / 4096.0f;
    float recon_loss = rs * invN;
    float l1   = l1s * invN;
    float ent  = -ents * invB;
    float mq0  = q0s * invB - 0.5f, mq1 = q1s * invB - 0.5f;
    float balance = mq0*mq0 + mq1*mq1;
    float spacing = sps * invB;
    out[0] = recon_loss + 0.05f*l1 + 0.01f*ent + 0.1f*balance + 0.1f*spacing;
}

extern "C" void kernel_launch(void* const* d_in, const int* in_sizes, int n_in,
                              void* d_out, int out_size, void* d_ws, size_t ws_size,
                              hipStream_t stream)
{
    const float* A      = (const float*)d_in[0];
    const float* W0     = (const float*)d_in[1];
    const float* B0     = (const float*)d_in[2];
    const float* W1     = (const float*)d_in[3];
    const float* B1     = (const float*)d_in[4];
    const float* W2     = (const float*)d_in[5];
    const float* B2     = (const float*)d_in[6];
    const float* proj_w = (const float*)d_in[7];
    const float* proj_b = (const float*)d_in[8];
    const float* val_w1 = (const float*)d_in[9];
    const float* val_b1 = (const float*)d_in[10];
    const float* val_w2 = (const float*)d_in[11];
    const float* val_b2 = (const float*)d_in[12];
    const float* pos_w1 = (const float*)d_in[13];
    const float* pos_b1 = (const float*)d_in[14];
    const float* pos_w2 = (const float*)d_in[15];
    const float* pos_b2 = (const float*)d_in[16];
    const float* res_w1 = (const float*)d_in[17];
    const float* res_b1 = (const float*)d_in[18];
    const float* res_w2 = (const float*)d_in[19];
    const float* res_b2 = (const float*)d_in[20];
    const float* mix_w  = (const float*)d_in[21];
    const float* mix_b  = (const float*)d_in[22];

    char* wsb = (char*)d_ws;
    float* accums = (float*)wsb;
    unsigned short* pooled = (unsigned short*)(wsb + 256);
    unsigned short* pkbuf  = (unsigned short*)(wsb + 256 + 2097152);
    unsigned short* rhbuf  = (unsigned short*)(wsb + 256 + 2097152 + (size_t)PK_TOTAL * 2);
    float* metabuf = (float*)(wsb + 256 + 2097152 + (size_t)PK_TOTAL * 2 + 2097152);
    unsigned char* wq1 = (unsigned char*)(wsb + 256 + 2097152 + (size_t)PK_TOTAL * 2 + 2097152
                                          + (size_t)4096 * 132 * 4);
    unsigned char* wq2 = wq1 + WQ4_BYTES;

    hipMemsetAsync(accums, 0, 64 * sizeof(float), stream);

    hipLaunchKernelGGL(pack_weights, dim3((PK_TOTAL + 255) / 256), dim3(256), 0, stream,
                       W0, W1, W2, proj_w, val_w1, pos_w1, res_w1,
                       val_w2, res_w2, pos_w2, mix_w, pkbuf, wq1, wq2);

    hipLaunchKernelGGL(conv_mfma_kernel, dim3(NB), dim3(256), 0, stream,
                       A, B0, B1, B2,
                       pkbuf + O_WP0, wq1, wq2, pooled);

    hipLaunchKernelGGL(heads_a_kernel, dim3(NB / 16), dim3(256), 0, stream,
                       pooled, proj_b, val_b1, pos_b1, res_b1, val_b2, pos_b2, mix_b,
                       pkbuf, rhbuf, metabuf, accums);

    hipLaunchKernelGGL(resid_loss_kernel, dim3(NB / 16 * 4), dim3(256), 0, stream,
                       A, rhbuf, res_b2, pkbuf, metabuf, accums);

    hipLaunchKernelGGL(finalize_kernel, dim3(1), dim3(1), 0, stream,
                       accums, (float*)d_out);
}

// Round 15
// 377.864 us; speedup vs baseline: 2.0563x; 1.9518x over previous
//
#include <hip/hip_runtime.h>

#define NB 4096

typedef __attribute__((ext_vector_type(8)))  __bf16 bf16x8;
typedef __attribute__((ext_vector_type(4)))  float  f32x4;
typedef __attribute__((ext_vector_type(16))) float  f32x16;
typedef __attribute__((ext_vector_type(8)))  int    i32x8;
typedef __attribute__((ext_vector_type(4)))  int    i32x4;

// gelu tanh-approx via sigmoid identity: x * rcp(1 + exp(-2y)), y = x(c0 + c1 x^2)
__device__ __forceinline__ float gelu_fast(float x){
    float x2 = x * x;
    float z  = x * (-1.59576912f - 0.07135482f * x2);   // -2y
    float e  = __expf(z);
    return x * __builtin_amdgcn_rcpf(1.0f + e);
}
__device__ __forceinline__ unsigned short f2bf(float x){
    unsigned b = __float_as_uint(x);
    b += 0x7fffu + ((b >> 16) & 1u);
    return (unsigned short)(b >> 16);
}
__device__ __forceinline__ unsigned char f2fp8(float x){
    int p = __builtin_amdgcn_cvt_pk_fp8_f32(x, x, 0, false);
    return (unsigned char)(p & 0xff);
}
// e2m1 fp4: values {0,0.5,1,1.5,2,3,4,6}, code = 3-bit (e:m), sign in bit 3.
__device__ __forceinline__ unsigned f2fp4(float x){
    unsigned s = (__float_as_uint(x) >> 31) & 1u;
    float m = fabsf(x);
    int c;
    if      (m < 0.25f) c = 0;
    else if (m < 0.75f) c = 1;
    else if (m < 1.25f) c = 2;
    else if (m < 1.75f) c = 3;
    else if (m < 2.5f)  c = 4;
    else if (m < 3.5f)  c = 5;
    else if (m < 5.0f)  c = 6;
    else                c = 7;
    return (s << 3) | (unsigned)c;
}

// ---------------- pack offsets (elements) ----------------
#define O_WP0  0
#define O_WP1  40960
#define O_WP2  368640
#define O_PROJ 696320
#define O_VAL1 761856
#define O_POS1 827392
#define O_RES1 892928
#define O_VAL2 958464
#define O_RES2 991232
#define O_POS2 1515520
#define O_MIX  1519616
#define PK_TOTAL 1523712

#define WQ4_BYTES 163840   // 256*1280 fp4 nibbles = 163840 bytes per conv layer

__device__ __forceinline__ unsigned short pack_std_elem(const float* W, int N, int t){
    int j = t & 7, lane = (t >> 3) & 63, rest = t >> 9;
    int ntcnt = N >> 4;
    int nt = rest % ntcnt, kk = rest / ntcnt;
    int n = nt*16 + (lane & 15), k = kk*32 + ((lane >> 4) << 3) + j;
    return f2bf(W[k * N + n]);
}
__device__ __forceinline__ unsigned short pack_pad_elem(const float* W, int Nreal, int t){
    int j = t & 7, lane = (t >> 3) & 63, kk = t >> 9;
    int n = lane & 15, k = kk*32 + ((lane >> 4) << 3) + j;
    return (n < Nreal) ? f2bf(W[k * Nreal + n]) : (unsigned short)0;
}
// fp4 conv pack for mfma_scale 32x32x64 blgp=4: per lane 32 k-elems = 16 B.
// byte t: byte=t&15, lane=(t>>4)&63, g=(t>>10)&7, S=t>>13 (0..19).
// n = g*32+(lane&31); k = S*64+(lane>>5)*32 + j (j = byte*2 + nibble, LSB-first);
// tap=k>>8, ci=k&255; value = W[n][ci][tap]*64 quantized to e2m1.
__device__ __forceinline__ unsigned char pack_fp4_byte(const float* W, int t){
    int byt = t & 15, lane = (t >> 4) & 63, g = (t >> 10) & 7, S = t >> 13;
    int n = g*32 + (lane & 31);
    int kbase = S*64 + ((lane >> 5) << 5) + (byt << 1);
    int k0 = kbase, k1 = kbase + 1;
    float v0 = W[n*1280 + (k0 & 255)*5 + (k0 >> 8)] * 64.0f;
    float v1 = W[n*1280 + (k1 & 255)*5 + (k1 >> 8)] * 64.0f;
    return (unsigned char)(f2fp4(v0) | (f2fp4(v1) << 4));
}

__global__ __launch_bounds__(256) void pack_weights(
    const float* __restrict__ W0, const float* __restrict__ W1, const float* __restrict__ W2,
    const float* __restrict__ proj_w, const float* __restrict__ val_w1,
    const float* __restrict__ pos_w1, const float* __restrict__ res_w1,
    const float* __restrict__ val_w2, const float* __restrict__ res_w2,
    const float* __restrict__ pos_w2, const float* __restrict__ mix_w,
    unsigned short* __restrict__ pk,
    unsigned char* __restrict__ wq1, unsigned char* __restrict__ wq2)
{
    int idx = blockIdx.x * 256 + threadIdx.x;
    if (idx >= PK_TOTAL) return;
    if (idx < O_WP1){
        int t = idx;
        int j = t & 7, lane = (t >> 3) & 63, nt = (t >> 9) & 7, s = t >> 12;   // s 0..9
        int co = nt*32 + (lane & 31);
        int tap = s >> 1, ci = ((s & 1) << 4) + ((lane >> 5) << 3) + j;
        pk[idx] = f2bf(W0[co*160 + ci*5 + tap]);
    } else if (idx < O_WP1 + WQ4_BYTES){
        wq1[idx - O_WP1] = pack_fp4_byte(W1, idx - O_WP1);
    } else if (idx < O_WP2){
        // gap
    } else if (idx < O_WP2 + WQ4_BYTES){
        wq2[idx - O_WP2] = pack_fp4_byte(W2, idx - O_WP2);
    } else if (idx < O_PROJ){
        // gap
    }
    else if (idx < O_VAL1) pk[idx] = pack_std_elem(proj_w, 256, idx - O_PROJ);
    else if (idx < O_POS1) pk[idx] = pack_std_elem(val_w1, 256, idx - O_VAL1);
    else if (idx < O_RES1) pk[idx] = pack_std_elem(pos_w1, 256, idx - O_POS1);
    else if (idx < O_VAL2) pk[idx] = pack_std_elem(res_w1, 256, idx - O_RES1);
    else if (idx < O_RES2) pk[idx] = pack_std_elem(val_w2, 128, idx - O_VAL2);
    else if (idx < O_POS2) pk[idx] = pack_std_elem(res_w2, 2048, idx - O_RES2);
    else if (idx < O_MIX)  pk[idx] = pack_pad_elem(pos_w2, 4, idx - O_POS2);
    else                   pk[idx] = pack_pad_elem(mix_w, 2, idx - O_MIX);
}

// ---------------- Kernel 1: MX fp8-A x fp4-B conv, 256 thr, 1 batch/block, 4 blk/CU ----------------
// R11-verified optimum: 4 waves = 4 col-groups of 64 (nn=2) x full 64 rows (mt=2); acc = 64.
// B fp4 (blgp=4 only — cbsz=4 fp4-A path triggers compiler scratch expansion, R12-R14).
// Weights pre-scaled x64, activations x8 -> EPI dequant 1/512.
#define HT_P 272
#define XT_S 40
#define INV512 0.001953125f
#define SCALE1 0x7F

__global__ __launch_bounds__(256, 4) void conv_mfma_kernel(
    const float* __restrict__ A,
    const float* __restrict__ B0, const float* __restrict__ B1, const float* __restrict__ B2,
    const unsigned short* __restrict__ wp0,
    const unsigned char* __restrict__ wq1, const unsigned char* __restrict__ wq2,
    unsigned short* __restrict__ pooled)
{
    __shared__ __align__(16) unsigned short xt[68 * XT_S];
    __shared__ __align__(16) unsigned char  ht8[68 * HT_P];

    const int tid  = threadIdx.x;
    const int b    = blockIdx.x;
    const int w    = tid >> 6;        // 0..3: 64-col output group
    const int lane = tid & 63;
    const int l31  = lane & 31;
    const int hi   = lane >> 5;
    const int hi8  = hi << 3;
    const int w64  = w << 6;

    // zero halo rows (taps reach rows 0,1,66,67)
    for (int i = tid; i < 4 * HT_P; i += 256){
        int r = i / HT_P, c = i - r * HT_P;
        int rr = (r < 2 ? r : r + 64);
        ht8[rr * HT_P + c] = 0;
    }
    if (tid < 128){
        int r = tid >> 5, c = tid & 31;
        int rr = (r < 2 ? r : r + 64);
        xt[rr * XT_S + c] = 0;
    }
    // pack input: 256 threads cover the batch (256*8 = 2048 elems)
    {
        const float* Ab = A + (size_t)b * 2048;
        int e0 = tid << 3;
        int t = e0 >> 5, c = e0 & 31;
        const float4* p = (const float4*)(Ab + e0);
        float4 v0 = p[0], v1 = p[1];
        union { unsigned short u[8]; bf16x8 v; } pkv;
        pkv.u[0]=f2bf(v0.x); pkv.u[1]=f2bf(v0.y); pkv.u[2]=f2bf(v0.z); pkv.u[3]=f2bf(v0.w);
        pkv.u[4]=f2bf(v1.x); pkv.u[5]=f2bf(v1.y); pkv.u[6]=f2bf(v1.z); pkv.u[7]=f2bf(v1.w);
        *(bf16x8*)&xt[(t + 2) * XT_S + c] = pkv.v;
    }
    __syncthreads();

    f32x16 acc[2][2];   // [mt][nn]

#define ZEROALL \
    { _Pragma("unroll") for (int mt = 0; mt < 2; ++mt) \
      _Pragma("unroll") for (int nn = 0; nn < 2; ++nn) \
      _Pragma("unroll") for (int r = 0; r < 16; ++r) acc[mt][nn][r] = 0.f; }

// ----- bf16 conv0 pieces (xt + wp0); fragment indexing verified R2-R11 -----
#define LOADAX(BUF, S) \
    { _Pragma("unroll") for (int mt = 0; mt < 2; ++mt) \
          BUF[mt] = *(const bf16x8*)&xt[((mt << 5) + l31 + ((S) >> 1)) * XT_S + (((S) & 1) << 4) + hi8]; }
#define LOADB0(BUF, S) \
    { _Pragma("unroll") for (int nn = 0; nn < 2; ++nn) \
          BUF[nn] = *(const bf16x8*)(b0ptr + nn * 512 + (S) * 4096); }
#define MFX(X_, B_) \
    { _Pragma("unroll") for (int mt = 0; mt < 2; ++mt) \
      _Pragma("unroll") for (int nn = 0; nn < 2; ++nn) \
          acc[mt][nn] = __builtin_amdgcn_mfma_f32_32x32x16_bf16(X_[mt], B_[nn], acc[mt][nn], 0, 0, 0); }

// ----- MX pieces: A fp8 from ht8 (verified R7-R11), B fp4 from wq (blgp=4, verified R11) -----
// A: row = mt*32 + l31 + tap(S>>2), k-off = (S&3)*64 + hi*32 (32 contig bytes)
#define LOADA_MX(DST, S) \
    { _Pragma("unroll") for (int mt = 0; mt < 2; ++mt) \
          DST[mt] = *(const i32x8*)&ht8[((mt << 5) + l31 + ((S) >> 2)) * HT_P + (((S) & 3) << 6) + (hi << 5)]; }
// B fp4: 16 B/lane into low half of i32x8 ring (upper half zeroed once, HW reads v[0:3])
#define LOADB4(DST, S, BPTR) \
    { _Pragma("unroll") for (int nn = 0; nn < 2; ++nn) \
          *(i32x4*)&DST[nn] = *(const i32x4*)((BPTR) + (size_t)(S) * 8192 + nn * 1024); }
#define MFMX4(A_, B_) \
    { _Pragma("unroll") for (int mt = 0; mt < 2; ++mt) \
      _Pragma("unroll") for (int nn = 0; nn < 2; ++nn) \
          acc[mt][nn] = __builtin_amdgcn_mfma_scale_f32_32x32x64_f8f6f4( \
              A_[mt], B_[nn], acc[mt][nn], 0, 4, 0, SCALE1, 0, SCALE1); }

// C/D: col = lane&31, row = (r&3) + 8*(r>>2) + 4*hi  [verified R2-R11]
#define EPI_C0(BIAS) \
    { float bvn[2]; \
      _Pragma("unroll") for (int nn = 0; nn < 2; ++nn) bvn[nn] = (BIAS)[w64 + (nn << 5) + l31]; \
      _Pragma("unroll") for (int mt = 0; mt < 2; ++mt) \
      _Pragma("unroll") for (int nn = 0; nn < 2; ++nn) \
      _Pragma("unroll") for (int r = 0; r < 16; ++r){ \
          int row = (mt << 5) + (r & 3) + ((r >> 2) << 3) + (hi << 2) + 2; \
          float v = gelu_fast(acc[mt][nn][r] + bvn[nn]); \
          ht8[row * HT_P + w64 + (nn << 5) + l31] = f2fp8(v * 8.0f); } }

#define EPI_MX(BIAS) \
    { float bvn[2]; \
      _Pragma("unroll") for (int nn = 0; nn < 2; ++nn) bvn[nn] = (BIAS)[w64 + (nn << 5) + l31]; \
      _Pragma("unroll") for (int mt = 0; mt < 2; ++mt) \
      _Pragma("unroll") for (int nn = 0; nn < 2; ++nn) \
      _Pragma("unroll") for (int r = 0; r < 16; ++r){ \
          int row = (mt << 5) + (r & 3) + ((r >> 2) << 3) + (hi << 2) + 2; \
          float v = gelu_fast(acc[mt][nn][r] * INV512 + bvn[nn]); \
          ht8[row * HT_P + w64 + (nn << 5) + l31] = f2fp8(v * 8.0f); } }

// fp4-B layer: 20 K-steps of 64, fully unrolled, A/B ring-2, loads after use (1-step lead)
#define CONV_MX4(WQ) \
    { const unsigned char* bptr = (WQ) + (size_t)((w << 11) + lane * 16); \
      i32x8 Bf[2][2]; i32x8 Af[2][2]; \
      _Pragma("unroll") for (int rr_ = 0; rr_ < 2; ++rr_) \
      _Pragma("unroll") for (int nn = 0; nn < 2; ++nn) \
      _Pragma("unroll") for (int e_ = 0; e_ < 8; ++e_) Bf[rr_][nn][e_] = 0; \
      LOADB4(Bf[0], 0, bptr); LOADA_MX(Af[0], 0); \
      LOADB4(Bf[1], 1, bptr); LOADA_MX(Af[1], 1); \
      _Pragma("unroll") \
      for (int s = 0; s < 20; ++s){ \
          MFMX4(Af[s & 1], Bf[s & 1]); \
          if (s + 2 < 20){ LOADB4(Bf[s & 1], s + 2, bptr); LOADA_MX(Af[s & 1], s + 2); } \
      } }

    // ---- conv0 (bf16, 10 K-steps of 16, fully unrolled, ring-2) ----
    ZEROALL;
    {
        const unsigned short* b0ptr = wp0 + (size_t)((w << 10) + lane * 8);
        bf16x8 Bc[2][2]; bf16x8 Xc[2][2];
        LOADB0(Bc[0], 0); LOADAX(Xc[0], 0);
        LOADB0(Bc[1], 1); LOADAX(Xc[1], 1);
        #pragma unroll
        for (int s = 0; s < 10; ++s){
            MFX(Xc[s & 1], Bc[s & 1]);
            if (s + 2 < 10){ LOADB0(Bc[s & 1], s + 2); LOADAX(Xc[s & 1], s + 2); }
        }
    }
    EPI_C0(B0);
    __syncthreads();

    // ---- conv1 (MX fp8 x fp4) ----
    ZEROALL;
    CONV_MX4(wq1);
    __syncthreads();
    EPI_MX(B1);
    __syncthreads();

    // ---- conv2 (MX fp8 x fp4) + mean pool ----
    ZEROALL;
    CONV_MX4(wq2);
    {
        float bvn[2];
        #pragma unroll
        for (int nn = 0; nn < 2; ++nn) bvn[nn] = B2[w64 + (nn << 5) + l31];
        #pragma unroll
        for (int nn = 0; nn < 2; ++nn){
            float a = 0.f;
            #pragma unroll
            for (int mt = 0; mt < 2; ++mt)
                #pragma unroll
                for (int r = 0; r < 16; ++r)
                    a += gelu_fast(acc[mt][nn][r] * INV512 + bvn[nn]);
            a += __shfl_xor(a, 32);
            if (hi == 0)
                pooled[(size_t)b * 256 + w64 + (nn << 5) + l31] = f2bf(a * (1.0f / 64.0f));
        }
    }
}

// ---------------- Kernel 2a: heads stages A-C, 16 batches/block (R7/R10-proven) ----------------
#define AS 264

__global__ __launch_bounds__(256) void heads_a_kernel(
    const unsigned short* __restrict__ pooled,
    const float* __restrict__ proj_b, const float* __restrict__ val_b1,
    const float* __restrict__ pos_b1, const float* __restrict__ res_b1,
    const float* __restrict__ val_b2, const float* __restrict__ pos_b2,
    const float* __restrict__ mix_b,
    const unsigned short* __restrict__ pk,
    unsigned short* __restrict__ rh, float* __restrict__ meta,
    float* __restrict__ accums)
{
    __shared__ unsigned short pb [16 * AS];
    __shared__ unsigned short eb [16 * AS];
    __shared__ unsigned short vb [16 * AS];
    __shared__ unsigned short phb[16 * AS];
    __shared__ unsigned short rhb[16 * AS];
    __shared__ float av [16 * 132];
    __shared__ float avs[16 * 132];
    __shared__ float psort[16][4];
    __shared__ int   rank [16][4];
    __shared__ float qsh  [16][2];
    __shared__ float mlsh [16][2];
    __shared__ float sposh[16][4];

    const int tid  = threadIdx.x;
    const int b0   = blockIdx.x * 16;
    const int w    = tid >> 6;
    const int lane = tid & 63;
    const int l15  = lane & 15;
    const int q    = lane >> 4;
    const int q8   = q << 3;
    const int q4   = q << 2;

    {
        int g = tid >> 4, seg = tid & 15;
        const unsigned short* ps = pooled + ((size_t)(b0 + g) << 8) + (seg << 4);
        bf16x8 a0 = *(const bf16x8*)ps;
        bf16x8 a1 = *(const bf16x8*)(ps + 8);
        *(bf16x8*)&pb[g * AS + (seg << 4)]     = a0;
        *(bf16x8*)&pb[g * AS + (seg << 4) + 8] = a1;
    }
    __syncthreads();

#define HGEMM256(ASRC, GOFF, BIAS, DST) \
    { f32x4 hacc[4]; \
      _Pragma("unroll") for (int nt = 0; nt < 4; ++nt) hacc[nt] = (f32x4){0.f,0.f,0.f,0.f}; \
      _Pragma("unroll") for (int kk = 0; kk < 8; ++kk){ \
          bf16x8 af = *(const bf16x8*)&(ASRC)[l15 * AS + (kk << 5) + q8]; \
          _Pragma("unroll") for (int nt = 0; nt < 4; ++nt){ \
              bf16x8 bfr = *(const bf16x8*)(pk + (GOFF) + (size_t)((((kk << 4) + (w << 2) + nt) << 6) + lane) * 8); \
              hacc[nt] = __builtin_amdgcn_mfma_f32_16x16x32_bf16(af, bfr, hacc[nt], 0, 0, 0); } } \
      _Pragma("unroll") for (int nt = 0; nt < 4; ++nt){ \
          int n = (w << 6) + (nt << 4) + l15; \
          float bv = (BIAS)[n]; \
          _Pragma("unroll") for (int r = 0; r < 4; ++r) \
              (DST)[(q4 + r) * AS + n] = f2bf(gelu_fast(hacc[nt][r] + bv)); } }

    HGEMM256(pb, O_PROJ, proj_b, eb);
    __syncthreads();

    HGEMM256(eb, O_VAL1, val_b1, vb);
    HGEMM256(eb, O_POS1, pos_b1, phb);
    HGEMM256(eb, O_RES1, res_b1, rhb);
    __syncthreads();

    {
        f32x4 acc2[2];
        #pragma unroll
        for (int nt = 0; nt < 2; ++nt) acc2[nt] = (f32x4){0.f,0.f,0.f,0.f};
        #pragma unroll
        for (int kk = 0; kk < 8; ++kk){
            bf16x8 af = *(const bf16x8*)&vb[l15 * AS + (kk << 5) + q8];
            #pragma unroll
            for (int nt = 0; nt < 2; ++nt){
                bf16x8 bfr = *(const bf16x8*)(pk + O_VAL2 + (size_t)(((kk*8 + w*2 + nt) << 6) + lane) * 8);
                acc2[nt] = __builtin_amdgcn_mfma_f32_16x16x32_bf16(af, bfr, acc2[nt], 0, 0, 0);
            }
        }
        #pragma unroll
        for (int nt = 0; nt < 2; ++nt){
            int j = (w << 5) + (nt << 4) + l15;
            float bv = val_b2[j];
            #pragma unroll
            for (int r = 0; r < 4; ++r)
                av[(q4 + r) * 132 + j] = acc2[nt][r] + bv;
        }
    }
    if (w == 0){
        f32x4 accp = (f32x4){0.f,0.f,0.f,0.f};
        #pragma unroll
        for (int kk = 0; kk < 8; ++kk){
            bf16x8 af  = *(const bf16x8*)&phb[l15 * AS + (kk << 5) + q8];
            bf16x8 bfr = *(const bf16x8*)(pk + O_POS2 + (size_t)((kk << 6) + lane) * 8);
            accp = __builtin_amdgcn_mfma_f32_16x16x32_bf16(af, bfr, accp, 0, 0, 0);
        }
        if (l15 < 4){
            float bv = pos_b2[l15];
            #pragma unroll
            for (int r = 0; r < 4; ++r){
                float raw = accp[r] + bv;
                sposh[q4 + r][l15] = 63.0f * __builtin_amdgcn_rcpf(1.0f + __expf(-raw));
            }
        }
    } else if (w == 1){
        f32x4 accm = (f32x4){0.f,0.f,0.f,0.f};
        #pragma unroll
        for (int kk = 0; kk < 8; ++kk){
            bf16x8 af  = *(const bf16x8*)&eb[l15 * AS + (kk << 5) + q8];
            bf16x8 bfr = *(const bf16x8*)(pk + O_MIX + (size_t)((kk << 6) + lane) * 8);
            accm = __builtin_amdgcn_mfma_f32_16x16x32_bf16(af, bfr, accm, 0, 0, 0);
        }
        if (l15 < 2){
            #pragma unroll
            for (int r = 0; r < 4; ++r)
                mlsh[q4 + r][l15] = accm[r] + mix_b[l15];
        }
    }
    __syncthreads();

    if (tid < 16){
        int g = tid;
        float sv[4] = { sposh[g][0], sposh[g][1], sposh[g][2], sposh[g][3] };
        #pragma unroll
        for (int i = 0; i < 4; ++i){
            int r = 0;
            #pragma unroll
            for (int jj = 0; jj < 4; ++jj){
                r += (sv[jj] < sv[i]) ? 1 : 0;
                if (jj < i) r += (sv[jj] == sv[i]) ? 1 : 0;
            }
            rank[g][i] = r;
            psort[g][r] = sv[i];
        }
        psort[g][0] = 0.0f; psort[g][3] = 63.0f;
        float p1 = psort[g][1], p2 = psort[g][2];
        float g1 = p1, g2 = p2 - p1, g3 = 63.0f - p2;
        const float MG = 10.5f;
        float r1 = fmaxf(MG - g1, 0.f), r2 = fmaxf(MG - g2, 0.f), r3 = fmaxf(MG - g3, 0.f);
        float sp = (r1*r1 + r2*r2 + r3*r3) * (1.0f / 3.0f);
        float l0 = mlsh[g][0], l1 = mlsh[g][1];
        float m = fmaxf(l0, l1);
        float e0 = __expf(l0 - m), e1 = __expf(l1 - m);
        float inv = 1.0f / (e0 + e1);
        float q0 = e0 * inv, q1 = e1 * inv;
        qsh[g][0] = q0; qsh[g][1] = q1;
        float entc = q0 * logf(q0 + 1e-8f) + q1 * logf(q1 + 1e-8f);
        atomicAdd(&accums[2], entc);
        atomicAdd(&accums[3], q0);
        atomicAdd(&accums[4], q1);
        atomicAdd(&accums[5], sp);
    }
    __syncthreads();

    #pragma unroll
    for (int u2 = 0; u2 < 8; ++u2){
        int idx2 = tid * 8 + u2;
        int g = idx2 >> 7, j = idx2 & 127;
        avs[g * 132 + rank[g][j >> 5] * 32 + (j & 31)] = av[g * 132 + j];
    }
    __syncthreads();

    {
        int g = tid >> 4, c16 = (tid & 15) << 4;
        bf16x8 a0 = *(const bf16x8*)&rhb[g * AS + c16];
        bf16x8 a1 = *(const bf16x8*)&rhb[g * AS + c16 + 8];
        unsigned short* dst = rh + ((size_t)(b0 + g) << 8) + c16;
        *(bf16x8*)dst       = a0;
        *(bf16x8*)(dst + 8) = a1;
    }
    if (tid < 132){
        for (int g = 0; g < 16; ++g){
            float v;
            if (tid < 128)       v = avs[g * 132 + tid];
            else if (tid == 128) v = psort[g][1];
            else if (tid == 129) v = psort[g][2];
            else if (tid == 130) v = qsh[g][0];
            else                 v = qsh[g][1];
            meta[(size_t)(b0 + g) * 132 + tid] = v;
        }
    }
}

// ---------------- Kernel 2b: residual GEMM + interp + recon/L1 losses ----------------
__global__ __launch_bounds__(256) void resid_loss_kernel(
    const float* __restrict__ A, const unsigned short* __restrict__ rh,
    const float* __restrict__ res_b2, const unsigned short* __restrict__ pk,
    const float* __restrict__ meta, float* __restrict__ accums)
{
    __shared__ float ml[16 * 132];
    __shared__ float wred[4], wred2[4];

    const int tid  = threadIdx.x;
    const int w    = tid >> 6;
    const int lane = tid & 63;
    const int l15  = lane & 15;
    const int q    = lane >> 4;
    const int q8   = q << 3;
    const int q4   = q << 2;
    const int bg   = blockIdx.x >> 2;
    const int cc   = blockIdx.x & 3;
    const int b0   = bg << 4;

    for (int i = tid; i < 16 * 132; i += 256)
        ml[i] = meta[(size_t)b0 * 132 + i];
    __syncthreads();

    f32x4 acc[8];
    #pragma unroll
    for (int nt = 0; nt < 8; ++nt) acc[nt] = (f32x4){0.f,0.f,0.f,0.f};
    #pragma unroll
    for (int kk = 0; kk < 8; ++kk){
        bf16x8 af = *(const bf16x8*)(rh + ((size_t)(b0 + l15) << 8) + (kk << 5) + q8);
        #pragma unroll
        for (int nt = 0; nt < 8; ++nt){
            int ntg = (cc << 5) + (w << 3) + nt;
            bf16x8 bfr = *(const bf16x8*)(pk + O_RES2 + (size_t)((kk << 7) + ntg) * 512 + (lane << 3));
            acc[nt] = __builtin_amdgcn_mfma_f32_16x16x32_bf16(af, bfr, acc[nt], 0, 0, 0);
        }
    }

    float lsq = 0.f, ll1 = 0.f;
    #pragma unroll
    for (int nt = 0; nt < 8; ++nt){
        int e = (cc << 9) + (w << 7) + (nt << 4) + l15;
        float rbv = res_b2[e];
        int t = e >> 5, d = e & 31;
        float tf = (float)t;
        #pragma unroll
        for (int r = 0; r < 4; ++r){
            int g = q4 + r;
            const float* mg = &ml[g * 132];
            float p1 = mg[128], p2 = mg[129], q0 = mg[130], q1 = mg[131];
            float res = acc[nt][r] + rbv;
            int cnt = (p1 <= tf) + (p2 <= tf) + (tf >= 63.0f);
            int idx = cnt < 2 ? cnt : 2;
            float left  = idx == 0 ? 0.0f : (idx == 1 ? p1 : p2);
            float right = idx == 0 ? p1   : (idx == 1 ? p2 : 63.0f);
            float wgt = (tf - left) / (right - left + 1e-8f);
            wgt = fminf(fmaxf(wgt, 0.f), 1.f);
            float vl = mg[idx * 32 + d];
            float vr = mg[idx * 32 + 32 + d];
            float coarse = vl + wgt * (vr - vl);
            float a = A[((size_t)(b0 + g) << 11) + e];
            float fine = coarse + res;
            float recon = q0 * coarse + q1 * fine;
            float dd = recon - a;
            lsq += dd * dd;
            ll1 += fabsf(res);
        }
    }
    #pragma unroll
    for (int off = 32; off > 0; off >>= 1){
        lsq += __shfl_down(lsq, off);
        ll1 += __shfl_down(ll1, off);
    }
    if (lane == 0){ wred[w] = lsq; wred2[w] = ll1; }
    __syncthreads();
    if (tid == 0){
        atomicAdd(&accums[0], wred[0] + wred[1] + wred[2] + wred[3]);
        atomicAdd(&accums[1], wred2[0] + wred2[1] + wred2[2] + wred2[3]);
    }
}

// ---------------- Kernel 3: finalize ----------------
__global__ void finalize_kernel(const float* __restrict__ accums, float* __restrict__ out){
    float rs = accums[0], l1s = accums[1], ents = accums[2];
    float q0s = accums[3], q1s = accums[4], sps = accums[5];
    const float invN = 1.0f / (4096.0f * 2048.0f);
    const float invB = 1.0f / 4096.0f;
    float recon_loss = rs * invN;
    float l1   = l1s * invN;
    float ent  = -ents * invB;
    float mq0  = q0s * invB - 0.5f, mq1 = q1s * invB - 0.5f;
    float balance = mq0*mq0 + mq1*mq1;
    float spacing = sps * invB;
    out[0] = recon_loss + 0.05f*l1 + 0.01f*ent + 0.1f*balance + 0.1f*spacing;
}

extern "C" void kernel_launch(void* const* d_in, const int* in_sizes, int n_in,
                              void* d_out, int out_size, void* d_ws, size_t ws_size,
                              hipStream_t stream)
{
    const float* A      = (const float*)d_in[0];
    const float* W0     = (const float*)d_in[1];
    const float* B0     = (const float*)d_in[2];
    const float* W1     = (const float*)d_in[3];
    const float* B1     = (const float*)d_in[4];
    const float* W2     = (const float*)d_in[5];
    const float* B2     = (const float*)d_in[6];
    const float* proj_w = (const float*)d_in[7];
    const float* proj_b = (const float*)d_in[8];
    const float* val_w1 = (const float*)d_in[9];
    const float* val_b1 = (const float*)d_in[10];
    const float* val_w2 = (const float*)d_in[11];
    const float* val_b2 = (const float*)d_in[12];
    const float* pos_w1 = (const float*)d_in[13];
    const float* pos_b1 = (const float*)d_in[14];
    const float* pos_w2 = (const float*)d_in[15];
    const float* pos_b2 = (const float*)d_in[16];
    const float* res_w1 = (const float*)d_in[17];
    const float* res_b1 = (const float*)d_in[18];
    const float* res_w2 = (const float*)d_in[19];
    const float* res_b2 = (const float*)d_in[20];
    const float* mix_w  = (const float*)d_in[21];
    const float* mix_b  = (const float*)d_in[22];

    char* wsb = (char*)d_ws;
    float* accums = (float*)wsb;
    unsigned short* pooled = (unsigned short*)(wsb + 256);
    unsigned short* pkbuf  = (unsigned short*)(wsb + 256 + 2097152);
    unsigned short* rhbuf  = (unsigned short*)(wsb + 256 + 2097152 + (size_t)PK_TOTAL * 2);
    float* metabuf = (float*)(wsb + 256 + 2097152 + (size_t)PK_TOTAL * 2 + 2097152);
    unsigned char* wq1 = (unsigned char*)(wsb + 256 + 2097152 + (size_t)PK_TOTAL * 2 + 2097152
                                          + (size_t)4096 * 132 * 4);
    unsigned char* wq2 = wq1 + WQ4_BYTES;

    hipMemsetAsync(accums, 0, 64 * sizeof(float), stream);

    hipLaunchKernelGGL(pack_weights, dim3((PK_TOTAL + 255) / 256), dim3(256), 0, stream,
                       W0, W1, W2, proj_w, val_w1, pos_w1, res_w1,
                       val_w2, res_w2, pos_w2, mix_w, pkbuf, wq1, wq2);

    hipLaunchKernelGGL(conv_mfma_kernel, dim3(NB), dim3(256), 0, stream,
                       A, B0, B1, B2,
                       pkbuf + O_WP0, wq1, wq2, pooled);

    hipLaunchKernelGGL(heads_a_kernel, dim3(NB / 16), dim3(256), 0, stream,
                       pooled, proj_b, val_b1, pos_b1, res_b1, val_b2, pos_b2, mix_b,
                       pkbuf, rhbuf, metabuf, accums);

    hipLaunchKernelGGL(resid_loss_kernel, dim3(NB / 16 * 4), dim3(256), 0, stream,
                       A, rhbuf, res_b2, pkbuf, metabuf, accums);

    hipLaunchKernelGGL(finalize_kernel, dim3(1), dim3(1), 0, stream,
                       accums, (float*)d_out);
}

// Round 16
// 347.175 us; speedup vs baseline: 2.2381x; 1.0884x over previous
//
#include <hip/hip_runtime.h>

#define NB 4096

typedef __attribute__((ext_vector_type(8)))  __bf16 bf16x8;
typedef __attribute__((ext_vector_type(4)))  float  f32x4;
typedef __attribute__((ext_vector_type(16))) float  f32x16;
typedef __attribute__((ext_vector_type(8)))  int    i32x8;
typedef __attribute__((ext_vector_type(4)))  int    i32x4;

// gelu tanh-approx via sigmoid identity: x * rcp(1 + exp(-2y)), y = x(c0 + c1 x^2)
__device__ __forceinline__ float gelu_fast(float x){
    float x2 = x * x;
    float z  = x * (-1.59576912f - 0.07135482f * x2);   // -2y
    float e  = __expf(z);
    return x * __builtin_amdgcn_rcpf(1.0f + e);
}
__device__ __forceinline__ unsigned short f2bf(float x){
    unsigned b = __float_as_uint(x);
    b += 0x7fffu + ((b >> 16) & 1u);
    return (unsigned short)(b >> 16);
}
__device__ __forceinline__ unsigned char f2fp8(float x){
    int p = __builtin_amdgcn_cvt_pk_fp8_f32(x, x, 0, false);
    return (unsigned char)(p & 0xff);
}
// e2m1 fp4: values {0,0.5,1,1.5,2,3,4,6}, code = 3-bit (e:m), sign in bit 3.
__device__ __forceinline__ unsigned f2fp4(float x){
    unsigned s = (__float_as_uint(x) >> 31) & 1u;
    float m = fabsf(x);
    int c;
    if      (m < 0.25f) c = 0;
    else if (m < 0.75f) c = 1;
    else if (m < 1.25f) c = 2;
    else if (m < 1.75f) c = 3;
    else if (m < 2.5f)  c = 4;
    else if (m < 3.5f)  c = 5;
    else if (m < 5.0f)  c = 6;
    else                c = 7;
    return (s << 3) | (unsigned)c;
}

// ---------------- pack offsets (elements) ----------------
#define O_WP0  0
#define O_WP1  40960
#define O_WP2  368640
#define O_PROJ 696320
#define O_VAL1 761856
#define O_POS1 827392
#define O_RES1 892928
#define O_VAL2 958464
#define O_RES2 991232
#define O_POS2 1515520
#define O_MIX  1519616
#define PK_TOTAL 1523712

#define WQ4_BYTES 163840   // 256*1280 fp4 nibbles = 163840 bytes per conv layer

__device__ __forceinline__ unsigned short pack_std_elem(const float* W, int N, int t){
    int j = t & 7, lane = (t >> 3) & 63, rest = t >> 9;
    int ntcnt = N >> 4;
    int nt = rest % ntcnt, kk = rest / ntcnt;
    int n = nt*16 + (lane & 15), k = kk*32 + ((lane >> 4) << 3) + j;
    return f2bf(W[k * N + n]);
}
__device__ __forceinline__ unsigned short pack_pad_elem(const float* W, int Nreal, int t){
    int j = t & 7, lane = (t >> 3) & 63, kk = t >> 9;
    int n = lane & 15, k = kk*32 + ((lane >> 4) << 3) + j;
    return (n < Nreal) ? f2bf(W[k * Nreal + n]) : (unsigned short)0;
}
// fp4 conv pack for mfma_scale 32x32x64 blgp=4: per lane 32 k-elems = 16 B, LSB-first.
__device__ __forceinline__ unsigned char pack_fp4_byte(const float* W, int t){
    int byt = t & 15, lane = (t >> 4) & 63, g = (t >> 10) & 7, S = t >> 13;
    int n = g*32 + (lane & 31);
    int kbase = S*64 + ((lane >> 5) << 5) + (byt << 1);
    int k0 = kbase, k1 = kbase + 1;
    float v0 = W[n*1280 + (k0 & 255)*5 + (k0 >> 8)] * 64.0f;
    float v1 = W[n*1280 + (k1 & 255)*5 + (k1 >> 8)] * 64.0f;
    return (unsigned char)(f2fp4(v0) | (f2fp4(v1) << 4));
}

__global__ __launch_bounds__(256) void pack_weights(
    const float* __restrict__ W0, const float* __restrict__ W1, const float* __restrict__ W2,
    const float* __restrict__ proj_w, const float* __restrict__ val_w1,
    const float* __restrict__ pos_w1, const float* __restrict__ res_w1,
    const float* __restrict__ val_w2, const float* __restrict__ res_w2,
    const float* __restrict__ pos_w2, const float* __restrict__ mix_w,
    unsigned short* __restrict__ pk,
    unsigned char* __restrict__ wq1, unsigned char* __restrict__ wq2)
{
    int idx = blockIdx.x * 256 + threadIdx.x;
    if (idx >= PK_TOTAL) return;
    if (idx < O_WP1){
        int t = idx;
        int j = t & 7, lane = (t >> 3) & 63, nt = (t >> 9) & 7, s = t >> 12;   // s 0..9
        int co = nt*32 + (lane & 31);
        int tap = s >> 1, ci = ((s & 1) << 4) + ((lane >> 5) << 3) + j;
        pk[idx] = f2bf(W0[co*160 + ci*5 + tap]);
    } else if (idx < O_WP1 + WQ4_BYTES){
        wq1[idx - O_WP1] = pack_fp4_byte(W1, idx - O_WP1);
    } else if (idx < O_WP2){
        // gap
    } else if (idx < O_WP2 + WQ4_BYTES){
        wq2[idx - O_WP2] = pack_fp4_byte(W2, idx - O_WP2);
    } else if (idx < O_PROJ){
        // gap
    }
    else if (idx < O_VAL1) pk[idx] = pack_std_elem(proj_w, 256, idx - O_PROJ);
    else if (idx < O_POS1) pk[idx] = pack_std_elem(val_w1, 256, idx - O_VAL1);
    else if (idx < O_RES1) pk[idx] = pack_std_elem(pos_w1, 256, idx - O_POS1);
    else if (idx < O_VAL2) pk[idx] = pack_std_elem(res_w1, 256, idx - O_RES1);
    else if (idx < O_RES2) pk[idx] = pack_std_elem(val_w2, 128, idx - O_VAL2);
    else if (idx < O_POS2) pk[idx] = pack_std_elem(res_w2, 2048, idx - O_RES2);
    else if (idx < O_MIX)  pk[idx] = pack_pad_elem(pos_w2, 4, idx - O_POS2);
    else                   pk[idx] = pack_pad_elem(mix_w, 2, idx - O_MIX);
}

// ---------------- Kernel 1: MX fp8-A x fp4-B conv (R11/R15-verified optimum) ----------------
#define HT_P 272
#define XT_S 40
#define INV512 0.001953125f
#define SCALE1 0x7F

__global__ __launch_bounds__(256, 4) void conv_mfma_kernel(
    const float* __restrict__ A,
    const float* __restrict__ B0, const float* __restrict__ B1, const float* __restrict__ B2,
    const unsigned short* __restrict__ wp0,
    const unsigned char* __restrict__ wq1, const unsigned char* __restrict__ wq2,
    unsigned short* __restrict__ pooled)
{
    __shared__ __align__(16) unsigned short xt[68 * XT_S];
    __shared__ __align__(16) unsigned char  ht8[68 * HT_P];

    const int tid  = threadIdx.x;
    const int b    = blockIdx.x;
    const int w    = tid >> 6;        // 0..3: 64-col output group
    const int lane = tid & 63;
    const int l31  = lane & 31;
    const int hi   = lane >> 5;
    const int hi8  = hi << 3;
    const int w64  = w << 6;

    for (int i = tid; i < 4 * HT_P; i += 256){
        int r = i / HT_P, c = i - r * HT_P;
        int rr = (r < 2 ? r : r + 64);
        ht8[rr * HT_P + c] = 0;
    }
    if (tid < 128){
        int r = tid >> 5, c = tid & 31;
        int rr = (r < 2 ? r : r + 64);
        xt[rr * XT_S + c] = 0;
    }
    {
        const float* Ab = A + (size_t)b * 2048;
        int e0 = tid << 3;
        int t = e0 >> 5, c = e0 & 31;
        const float4* p = (const float4*)(Ab + e0);
        float4 v0 = p[0], v1 = p[1];
        union { unsigned short u[8]; bf16x8 v; } pkv;
        pkv.u[0]=f2bf(v0.x); pkv.u[1]=f2bf(v0.y); pkv.u[2]=f2bf(v0.z); pkv.u[3]=f2bf(v0.w);
        pkv.u[4]=f2bf(v1.x); pkv.u[5]=f2bf(v1.y); pkv.u[6]=f2bf(v1.z); pkv.u[7]=f2bf(v1.w);
        *(bf16x8*)&xt[(t + 2) * XT_S + c] = pkv.v;
    }
    __syncthreads();

    f32x16 acc[2][2];   // [mt][nn]

#define ZEROALL \
    { _Pragma("unroll") for (int mt = 0; mt < 2; ++mt) \
      _Pragma("unroll") for (int nn = 0; nn < 2; ++nn) \
      _Pragma("unroll") for (int r = 0; r < 16; ++r) acc[mt][nn][r] = 0.f; }

#define LOADAX(BUF, S) \
    { _Pragma("unroll") for (int mt = 0; mt < 2; ++mt) \
          BUF[mt] = *(const bf16x8*)&xt[((mt << 5) + l31 + ((S) >> 1)) * XT_S + (((S) & 1) << 4) + hi8]; }
#define LOADB0(BUF, S) \
    { _Pragma("unroll") for (int nn = 0; nn < 2; ++nn) \
          BUF[nn] = *(const bf16x8*)(b0ptr + nn * 512 + (S) * 4096); }
#define MFX(X_, B_) \
    { _Pragma("unroll") for (int mt = 0; mt < 2; ++mt) \
      _Pragma("unroll") for (int nn = 0; nn < 2; ++nn) \
          acc[mt][nn] = __builtin_amdgcn_mfma_f32_32x32x16_bf16(X_[mt], B_[nn], acc[mt][nn], 0, 0, 0); }

#define LOADA_MX(DST, S) \
    { _Pragma("unroll") for (int mt = 0; mt < 2; ++mt) \
          DST[mt] = *(const i32x8*)&ht8[((mt << 5) + l31 + ((S) >> 2)) * HT_P + (((S) & 3) << 6) + (hi << 5)]; }
#define LOADB4(DST, S, BPTR) \
    { _Pragma("unroll") for (int nn = 0; nn < 2; ++nn) \
          *(i32x4*)&DST[nn] = *(const i32x4*)((BPTR) + (size_t)(S) * 8192 + nn * 1024); }
#define MFMX4(A_, B_) \
    { _Pragma("unroll") for (int mt = 0; mt < 2; ++mt) \
      _Pragma("unroll") for (int nn = 0; nn < 2; ++nn) \
          acc[mt][nn] = __builtin_amdgcn_mfma_scale_f32_32x32x64_f8f6f4( \
              A_[mt], B_[nn], acc[mt][nn], 0, 4, 0, SCALE1, 0, SCALE1); }

#define EPI_C0(BIAS) \
    { float bvn[2]; \
      _Pragma("unroll") for (int nn = 0; nn < 2; ++nn) bvn[nn] = (BIAS)[w64 + (nn << 5) + l31]; \
      _Pragma("unroll") for (int mt = 0; mt < 2; ++mt) \
      _Pragma("unroll") for (int nn = 0; nn < 2; ++nn) \
      _Pragma("unroll") for (int r = 0; r < 16; ++r){ \
          int row = (mt << 5) + (r & 3) + ((r >> 2) << 3) + (hi << 2) + 2; \
          float v = gelu_fast(acc[mt][nn][r] + bvn[nn]); \
          ht8[row * HT_P + w64 + (nn << 5) + l31] = f2fp8(v * 8.0f); } }

#define EPI_MX(BIAS) \
    { float bvn[2]; \
      _Pragma("unroll") for (int nn = 0; nn < 2; ++nn) bvn[nn] = (BIAS)[w64 + (nn << 5) + l31]; \
      _Pragma("unroll") for (int mt = 0; mt < 2; ++mt) \
      _Pragma("unroll") for (int nn = 0; nn < 2; ++nn) \
      _Pragma("unroll") for (int r = 0; r < 16; ++r){ \
          int row = (mt << 5) + (r & 3) + ((r >> 2) << 3) + (hi << 2) + 2; \
          float v = gelu_fast(acc[mt][nn][r] * INV512 + bvn[nn]); \
          ht8[row * HT_P + w64 + (nn << 5) + l31] = f2fp8(v * 8.0f); } }

#define CONV_MX4(WQ) \
    { const unsigned char* bptr = (WQ) + (size_t)((w << 11) + lane * 16); \
      i32x8 Bf[2][2]; i32x8 Af[2][2]; \
      _Pragma("unroll") for (int rr_ = 0; rr_ < 2; ++rr_) \
      _Pragma("unroll") for (int nn = 0; nn < 2; ++nn) \
      _Pragma("unroll") for (int e_ = 0; e_ < 8; ++e_) Bf[rr_][nn][e_] = 0; \
      LOADB4(Bf[0], 0, bptr); LOADA_MX(Af[0], 0); \
      LOADB4(Bf[1], 1, bptr); LOADA_MX(Af[1], 1); \
      _Pragma("unroll") \
      for (int s = 0; s < 20; ++s){ \
          MFMX4(Af[s & 1], Bf[s & 1]); \
          if (s + 2 < 20){ LOADB4(Bf[s & 1], s + 2, bptr); LOADA_MX(Af[s & 1], s + 2); } \
      } }

    // ---- conv0 (bf16) ----
    ZEROALL;
    {
        const unsigned short* b0ptr = wp0 + (size_t)((w << 10) + lane * 8);
        bf16x8 Bc[2][2]; bf16x8 Xc[2][2];
        LOADB0(Bc[0], 0); LOADAX(Xc[0], 0);
        LOADB0(Bc[1], 1); LOADAX(Xc[1], 1);
        #pragma unroll
        for (int s = 0; s < 10; ++s){
            MFX(Xc[s & 1], Bc[s & 1]);
            if (s + 2 < 10){ LOADB0(Bc[s & 1], s + 2); LOADAX(Xc[s & 1], s + 2); }
        }
    }
    EPI_C0(B0);
    __syncthreads();

    // ---- conv1 (MX fp8 x fp4) ----
    ZEROALL;
    CONV_MX4(wq1);
    __syncthreads();
    EPI_MX(B1);
    __syncthreads();

    // ---- conv2 (MX fp8 x fp4) + mean pool ----
    ZEROALL;
    CONV_MX4(wq2);
    {
        float bvn[2];
        #pragma unroll
        for (int nn = 0; nn < 2; ++nn) bvn[nn] = B2[w64 + (nn << 5) + l31];
        #pragma unroll
        for (int nn = 0; nn < 2; ++nn){
            float a = 0.f;
            #pragma unroll
            for (int mt = 0; mt < 2; ++mt)
                #pragma unroll
                for (int r = 0; r < 16; ++r)
                    a += gelu_fast(acc[mt][nn][r] * INV512 + bvn[nn]);
            a += __shfl_xor(a, 32);
            if (hi == 0)
                pooled[(size_t)b * 256 + w64 + (nn << 5) + l31] = f2bf(a * (1.0f / 64.0f));
        }
    }
}

// ---------------- Kernel 2a: heads, 512 thr (8 waves), wave-parallel stage B ----------------
// Stage A: 8 waves x 32 cols. Stage B: waves 0-1 val1, 2-3 pos1, 4-5 res1 (128 cols each),
// wave 6 mix (reads eb). Stage C: waves 0-3 val2, wave 4 pos2. 16 batches/block, 256 blocks.
#define AS 264

__global__ __launch_bounds__(512) void heads_a_kernel(
    const unsigned short* __restrict__ pooled,
    const float* __restrict__ proj_b, const float* __restrict__ val_b1,
    const float* __restrict__ pos_b1, const float* __restrict__ res_b1,
    const float* __restrict__ val_b2, const float* __restrict__ pos_b2,
    const float* __restrict__ mix_b,
    const unsigned short* __restrict__ pk,
    unsigned short* __restrict__ rh, float* __restrict__ meta,
    float* __restrict__ accums)
{
    __shared__ unsigned short pb [16 * AS];
    __shared__ unsigned short eb [16 * AS];
    __shared__ unsigned short vb [16 * AS];
    __shared__ unsigned short phb[16 * AS];
    __shared__ unsigned short rhb[16 * AS];
    __shared__ float av [16 * 132];
    __shared__ float avs[16 * 132];
    __shared__ float psort[16][4];
    __shared__ int   rank [16][4];
    __shared__ float qsh  [16][2];
    __shared__ float mlsh [16][2];
    __shared__ float sposh[16][4];

    const int tid  = threadIdx.x;
    const int b0   = blockIdx.x * 16;
    const int w    = tid >> 6;        // 0..7
    const int lane = tid & 63;
    const int l15  = lane & 15;
    const int q    = lane >> 4;
    const int q8   = q << 3;
    const int q4   = q << 2;

    if (tid < 256){
        int g = tid >> 4, seg = tid & 15;
        const unsigned short* ps = pooled + ((size_t)(b0 + g) << 8) + (seg << 4);
        bf16x8 a0 = *(const bf16x8*)ps;
        bf16x8 a1 = *(const bf16x8*)(ps + 8);
        *(bf16x8*)&pb[g * AS + (seg << 4)]     = a0;
        *(bf16x8*)&pb[g * AS + (seg << 4) + 8] = a1;
    }
    __syncthreads();

    // Stage A: proj -> eb, 8 waves x 32 cols (group = (w<<1)+nt, nt<2)
    {
        f32x4 hacc[2];
        #pragma unroll
        for (int nt = 0; nt < 2; ++nt) hacc[nt] = (f32x4){0.f,0.f,0.f,0.f};
        #pragma unroll
        for (int kk = 0; kk < 8; ++kk){
            bf16x8 af = *(const bf16x8*)&pb[l15 * AS + (kk << 5) + q8];
            #pragma unroll
            for (int nt = 0; nt < 2; ++nt){
                bf16x8 bfr = *(const bf16x8*)(pk + O_PROJ + (size_t)((((kk << 4) + (w << 1) + nt) << 6) + lane) * 8);
                hacc[nt] = __builtin_amdgcn_mfma_f32_16x16x32_bf16(af, bfr, hacc[nt], 0, 0, 0);
            }
        }
        #pragma unroll
        for (int nt = 0; nt < 2; ++nt){
            int n = (w << 5) + (nt << 4) + l15;
            float bv = proj_b[n];
            #pragma unroll
            for (int r = 0; r < 4; ++r)
                eb[(q4 + r) * AS + n] = f2bf(gelu_fast(hacc[nt][r] + bv));
        }
    }
    __syncthreads();

    // Stage B: wave-parallel. pair = w>>1 (0:val1, 1:pos1, 2:res1); half = w&1 (128 cols).
    if (w < 6){
        const int pair = w >> 1, half = w & 1;
        const int goff = (pair == 0) ? O_VAL1 : (pair == 1) ? O_POS1 : O_RES1;
        const float* bias = (pair == 0) ? val_b1 : (pair == 1) ? pos_b1 : res_b1;
        unsigned short* dst = (pair == 0) ? vb : (pair == 1) ? phb : rhb;
        f32x4 hacc[8];
        #pragma unroll
        for (int nt = 0; nt < 8; ++nt) hacc[nt] = (f32x4){0.f,0.f,0.f,0.f};
        #pragma unroll
        for (int kk = 0; kk < 8; ++kk){
            bf16x8 af = *(const bf16x8*)&eb[l15 * AS + (kk << 5) + q8];
            #pragma unroll
            for (int nt = 0; nt < 8; ++nt){
                bf16x8 bfr = *(const bf16x8*)(pk + goff + (size_t)((((kk << 4) + (half << 3) + nt) << 6) + lane) * 8);
                hacc[nt] = __builtin_amdgcn_mfma_f32_16x16x32_bf16(af, bfr, hacc[nt], 0, 0, 0);
            }
        }
        #pragma unroll
        for (int nt = 0; nt < 8; ++nt){
            int n = (half << 7) + (nt << 4) + l15;
            float bv = bias[n];
            #pragma unroll
            for (int r = 0; r < 4; ++r)
                dst[(q4 + r) * AS + n] = f2bf(gelu_fast(hacc[nt][r] + bv));
        }
    } else if (w == 6){
        f32x4 accm = (f32x4){0.f,0.f,0.f,0.f};
        #pragma unroll
        for (int kk = 0; kk < 8; ++kk){
            bf16x8 af  = *(const bf16x8*)&eb[l15 * AS + (kk << 5) + q8];
            bf16x8 bfr = *(const bf16x8*)(pk + O_MIX + (size_t)((kk << 6) + lane) * 8);
            accm = __builtin_amdgcn_mfma_f32_16x16x32_bf16(af, bfr, accm, 0, 0, 0);
        }
        if (l15 < 2){
            #pragma unroll
            for (int r = 0; r < 4; ++r)
                mlsh[q4 + r][l15] = accm[r] + mix_b[l15];
        }
    }
    __syncthreads();

    // Stage C: waves 0-3 val2 (N=128, group = w*2+nt), wave 4 pos2.
    if (w < 4){
        f32x4 acc2[2];
        #pragma unroll
        for (int nt = 0; nt < 2; ++nt) acc2[nt] = (f32x4){0.f,0.f,0.f,0.f};
        #pragma unroll
        for (int kk = 0; kk < 8; ++kk){
            bf16x8 af = *(const bf16x8*)&vb[l15 * AS + (kk << 5) + q8];
            #pragma unroll
            for (int nt = 0; nt < 2; ++nt){
                bf16x8 bfr = *(const bf16x8*)(pk + O_VAL2 + (size_t)(((kk*8 + w*2 + nt) << 6) + lane) * 8);
                acc2[nt] = __builtin_amdgcn_mfma_f32_16x16x32_bf16(af, bfr, acc2[nt], 0, 0, 0);
            }
        }
        #pragma unroll
        for (int nt = 0; nt < 2; ++nt){
            int j = (w << 5) + (nt << 4) + l15;
            float bv = val_b2[j];
            #pragma unroll
            for (int r = 0; r < 4; ++r)
                av[(q4 + r) * 132 + j] = acc2[nt][r] + bv;
        }
    } else if (w == 4){
        f32x4 accp = (f32x4){0.f,0.f,0.f,0.f};
        #pragma unroll
        for (int kk = 0; kk < 8; ++kk){
            bf16x8 af  = *(const bf16x8*)&phb[l15 * AS + (kk << 5) + q8];
            bf16x8 bfr = *(const bf16x8*)(pk + O_POS2 + (size_t)((kk << 6) + lane) * 8);
            accp = __builtin_amdgcn_mfma_f32_16x16x32_bf16(af, bfr, accp, 0, 0, 0);
        }
        if (l15 < 4){
            float bv = pos_b2[l15];
            #pragma unroll
            for (int r = 0; r < 4; ++r){
                float raw = accp[r] + bv;
                sposh[q4 + r][l15] = 63.0f * __builtin_amdgcn_rcpf(1.0f + __expf(-raw));
            }
        }
    }
    __syncthreads();

    if (tid < 16){
        int g = tid;
        float sv[4] = { sposh[g][0], sposh[g][1], sposh[g][2], sposh[g][3] };
        #pragma unroll
        for (int i = 0; i < 4; ++i){
            int r = 0;
            #pragma unroll
            for (int jj = 0; jj < 4; ++jj){
                r += (sv[jj] < sv[i]) ? 1 : 0;
                if (jj < i) r += (sv[jj] == sv[i]) ? 1 : 0;
            }
            rank[g][i] = r;
            psort[g][r] = sv[i];
        }
        psort[g][0] = 0.0f; psort[g][3] = 63.0f;
        float p1 = psort[g][1], p2 = psort[g][2];
        float g1 = p1, g2 = p2 - p1, g3 = 63.0f - p2;
        const float MG = 10.5f;
        float r1 = fmaxf(MG - g1, 0.f), r2 = fmaxf(MG - g2, 0.f), r3 = fmaxf(MG - g3, 0.f);
        float sp = (r1*r1 + r2*r2 + r3*r3) * (1.0f / 3.0f);
        float l0 = mlsh[g][0], l1 = mlsh[g][1];
        float m = fmaxf(l0, l1);
        float e0 = __expf(l0 - m), e1 = __expf(l1 - m);
        float inv = 1.0f / (e0 + e1);
        float q0 = e0 * inv, q1 = e1 * inv;
        qsh[g][0] = q0; qsh[g][1] = q1;
        float entc = q0 * logf(q0 + 1e-8f) + q1 * logf(q1 + 1e-8f);
        atomicAdd(&accums[2], entc);
        atomicAdd(&accums[3], q0);
        atomicAdd(&accums[4], q1);
        atomicAdd(&accums[5], sp);
    }
    __syncthreads();

    #pragma unroll
    for (int u2 = 0; u2 < 4; ++u2){
        int idx2 = tid * 4 + u2;
        int g = idx2 >> 7, j = idx2 & 127;
        avs[g * 132 + rank[g][j >> 5] * 32 + (j & 31)] = av[g * 132 + j];
    }
    __syncthreads();

    if (tid < 256){
        int g = tid >> 4, c16 = (tid & 15) << 4;
        bf16x8 a0 = *(const bf16x8*)&rhb[g * AS + c16];
        bf16x8 a1 = *(const bf16x8*)&rhb[g * AS + c16 + 8];
        unsigned short* dst = rh + ((size_t)(b0 + g) << 8) + c16;
        *(bf16x8*)dst       = a0;
        *(bf16x8*)(dst + 8) = a1;
    }
    if (tid < 132){
        for (int g = 0; g < 16; ++g){
            float v;
            if (tid < 128)       v = avs[g * 132 + tid];
            else if (tid == 128) v = psort[g][1];
            else if (tid == 129) v = psort[g][2];
            else if (tid == 130) v = qsh[g][0];
            else                 v = qsh[g][1];
            meta[(size_t)(b0 + g) * 132 + tid] = v;
        }
    }
}

// ---------------- Kernel 2b: residual GEMM + interp + recon/L1 losses ----------------
__global__ __launch_bounds__(256) void resid_loss_kernel(
    const float* __restrict__ A, const unsigned short* __restrict__ rh,
    const float* __restrict__ res_b2, const unsigned short* __restrict__ pk,
    const float* __restrict__ meta, float* __restrict__ accums)
{
    __shared__ float ml[16 * 132];
    __shared__ float wred[4], wred2[4];

    const int tid  = threadIdx.x;
    const int w    = tid >> 6;
    const int lane = tid & 63;
    const int l15  = lane & 15;
    const int q    = lane >> 4;
    const int q8   = q << 3;
    const int q4   = q << 2;
    const int bg   = blockIdx.x >> 2;
    const int cc   = blockIdx.x & 3;
    const int b0   = bg << 4;

    for (int i = tid; i < 16 * 132; i += 256)
        ml[i] = meta[(size_t)b0 * 132 + i];
    __syncthreads();

    f32x4 acc[8];
    #pragma unroll
    for (int nt = 0; nt < 8; ++nt) acc[nt] = (f32x4){0.f,0.f,0.f,0.f};
    #pragma unroll
    for (int kk = 0; kk < 8; ++kk){
        bf16x8 af = *(const bf16x8*)(rh + ((size_t)(b0 + l15) << 8) + (kk << 5) + q8);
        #pragma unroll
        for (int nt = 0; nt < 8; ++nt){
            int ntg = (cc << 5) + (w << 3) + nt;
            bf16x8 bfr = *(const bf16x8*)(pk + O_RES2 + (size_t)((kk << 7) + ntg) * 512 + (lane << 3));
            acc[nt] = __builtin_amdgcn_mfma_f32_16x16x32_bf16(af, bfr, acc[nt], 0, 0, 0);
        }
    }

    float lsq = 0.f, ll1 = 0.f;
    #pragma unroll
    for (int nt = 0; nt < 8; ++nt){
        int e = (cc << 9) + (w << 7) + (nt << 4) + l15;
        float rbv = res_b2[e];
        int t = e >> 5, d = e & 31;
        float tf = (float)t;
        #pragma unroll
        for (int r = 0; r < 4; ++r){
            int g = q4 + r;
            const float* mg = &ml[g * 132];
            float p1 = mg[128], p2 = mg[129], q0 = mg[130], q1 = mg[131];
            float res = acc[nt][r] + rbv;
            int cnt = (p1 <= tf) + (p2 <= tf) + (tf >= 63.0f);
            int idx = cnt < 2 ? cnt : 2;
            float left  = idx == 0 ? 0.0f : (idx == 1 ? p1 : p2);
            float right = idx == 0 ? p1   : (idx == 1 ? p2 : 63.0f);
            float wgt = (tf - left) / (right - left + 1e-8f);
            wgt = fminf(fmaxf(wgt, 0.f), 1.f);
            float vl = mg[idx * 32 + d];
            float vr = mg[idx * 32 + 32 + d];
            float coarse = vl + wgt * (vr - vl);
            float a = A[((size_t)(b0 + g) << 11) + e];
            float fine = coarse + res;
            float recon = q0 * coarse + q1 * fine;
            float dd = recon - a;
            lsq += dd * dd;
            ll1 += fabsf(res);
        }
    }
    #pragma unroll
    for (int off = 32; off > 0; off >>= 1){
        lsq += __shfl_down(lsq, off);
        ll1 += __shfl_down(ll1, off);
    }
    if (lane == 0){ wred[w] = lsq; wred2[w] = ll1; }
    __syncthreads();
    if (tid == 0){
        atomicAdd(&accums[0], wred[0] + wred[1] + wred[2] + wred[3]);
        atomicAdd(&accums[1], wred2[0] + wred2[1] + wred2[2] + wred2[3]);
    }
}

// ---------------- Kernel 3: finalize ----------------
__global__ void finalize_kernel(const float* __restrict__ accums, float* __restrict__ out){
    float rs = accums[0], l1s = accums[1], ents = accums[2];
    float q0s = accums[3], q1s = accums[4], sps = accums[5];
    const float invN = 1.0f / (4096.0f * 2048.0f);
    const float invB = 1.0f / 4096.0f;
    float recon_loss = rs * invN;
    float l1   = l1s * invN;
    float ent  = -ents * invB;
    float mq0  = q0s * invB - 0.5f, mq1 = q1s * invB - 0.5f;
    float balance = mq0*mq0 + mq1*mq1;
    float spacing = sps * invB;
    out[0] = recon_loss + 0.05f*l1 + 0.01f*ent + 0.1f*balance + 0.1f*spacing;
}

extern "C" void kernel_launch(void* const* d_in, const int* in_sizes, int n_in,
                              void* d_out, int out_size, void* d_ws, size_t ws_size,
                              hipStream_t stream)
{
    const float* A      = (const float*)d_in[0];
    const float* W0     = (const float*)d_in[1];
    const float* B0     = (const float*)d_in[2];
    const float* W1     = (const float*)d_in[3];
    const float* B1     = (const float*)d_in[4];
    const float* W2     = (const float*)d_in[5];
    const float* B2     = (const float*)d_in[6];
    const float* proj_w = (const float*)d_in[7];
    const float* proj_b = (const float*)d_in[8];
    const float* val_w1 = (const float*)d_in[9];
    const float* val_b1 = (const float*)d_in[10];
    const float* val_w2 = (const float*)d_in[11];
    const float* val_b2 = (const float*)d_in[12];
    const float* pos_w1 = (const float*)d_in[13];
    const float* pos_b1 = (const float*)d_in[14];
    const float* pos_w2 = (const float*)d_in[15];
    const float* pos_b2 = (const float*)d_in[16];
    const float* res_w1 = (const float*)d_in[17];
    const float* res_b1 = (const float*)d_in[18];
    const float* res_w2 = (const float*)d_in[19];
    const float* res_b2 = (const float*)d_in[20];
    const float* mix_w  = (const float*)d_in[21];
    const float* mix_b  = (const float*)d_in[22];

    char* wsb = (char*)d_ws;
    float* accums = (float*)wsb;
    unsigned short* pooled = (unsigned short*)(wsb + 256);
    unsigned short* pkbuf  = (unsigned short*)(wsb + 256 + 2097152);
    unsigned short* rhbuf  = (unsigned short*)(wsb + 256 + 2097152 + (size_t)PK_TOTAL * 2);
    float* metabuf = (float*)(wsb + 256 + 2097152 + (size_t)PK_TOTAL * 2 + 2097152);
    unsigned char* wq1 = (unsigned char*)(wsb + 256 + 2097152 + (size_t)PK_TOTAL * 2 + 2097152
                                          + (size_t)4096 * 132 * 4);
    unsigned char* wq2 = wq1 + WQ4_BYTES;

    hipMemsetAsync(accums, 0, 64 * sizeof(float), stream);

    hipLaunchKernelGGL(pack_weights, dim3((PK_TOTAL + 255) / 256), dim3(256), 0, stream,
                       W0, W1, W2, proj_w, val_w1, pos_w1, res_w1,
                       val_w2, res_w2, pos_w2, mix_w, pkbuf, wq1, wq2);

    hipLaunchKernelGGL(conv_mfma_kernel, dim3(NB), dim3(256), 0, stream,
                       A, B0, B1, B2,
                       pkbuf + O_WP0, wq1, wq2, pooled);

    hipLaunchKernelGGL(heads_a_kernel, dim3(NB / 16), dim3(512), 0, stream,
                       pooled, proj_b, val_b1, pos_b1, res_b1, val_b2, pos_b2, mix_b,
                       pkbuf, rhbuf, metabuf, accums);

    hipLaunchKernelGGL(resid_loss_kernel, dim3(NB / 16 * 4), dim3(256), 0, stream,
                       A, rhbuf, res_b2, pkbuf, metabuf, accums);

    hipLaunchKernelGGL(finalize_kernel, dim3(1), dim3(1), 0, stream,
                       accums, (float*)d_out);
}